// Round 2
// baseline (719.815 us; speedup 1.0000x reference)
//
#include <hip/hip_runtime.h>
#include <hip/hip_bf16.h>
#include <cmath>

// Problem constants (B=2, N=1000, k=8 from reference)
#define NB 2
#define NP 1000
#define KNN 8
#define NPAD 1024
#define PPAIR 499500  // N*(N-1)/2

typedef __hip_bfloat16 bf16;

__device__ __forceinline__ float b2f(bf16 v) { return __bfloat162float(v); }

// Workspace layout (float offsets), all 16B-aligned
#define OFF_POS    0
#define OFF_C1W1   6000
#define OFF_C1B1   6096
#define OFF_C1W2   6112
#define OFF_C1B2   6624
#define OFF_C2W1   6656
#define OFF_C2B1   10752
#define OFF_C2W2   10816
#define OFF_C2B2   19008
#define OFF_C3W1   19136
#define OFF_C3B1   84672
#define OFF_C3W2   84928
#define OFF_C3B2   216000
#define OFF_SMW1   216512
#define OFF_SMB1   388544
#define OFF_SMW2   388800
#define OFF_SMB2   421568
#define OFF_ECW1   421696
#define OFF_ECB1   470848
#define OFF_ECW2   470976
#define OFF_ECB2   471104
#define OFF_X1     471112
#define OFF_X2     535112
#define OFF_X3     791112
#define OFF_SF     1815112
#define OFF_G      2071112
#define OFF_HI     2071368
#define OFF_HJ     2327368
#define OFF_HG     2583368
#define OFF_FLAG   2583624   // int
#define OFF_NIDX   2583632   // 16000 ints

// ---------------- dtype detection ----------------
// Interpret pos as bf16; true bf16 N(0,1) data has max|v| ~ 4.
// f32 data read as bf16 halves contains random-exponent garbage -> max >> 1e6.
__global__ void detect_kernel(const void* pos, int* flag) {
    __shared__ float red[256];
    const unsigned short* p = (const unsigned short*)pos;
    float m = 0.f;
    for (int t = threadIdx.x; t < 6000; t += 256) {
        unsigned int u = ((unsigned int)p[t]) << 16;
        float v = fabsf(__uint_as_float(u));
        if (!isfinite(v)) v = 1e30f;   // NaN/Inf in bf16 interp => definitely f32 data
        m = fmaxf(m, v);
    }
    red[threadIdx.x] = m;
    __syncthreads();
    for (int s = 128; s > 0; s >>= 1) {
        if (threadIdx.x < s) red[threadIdx.x] = fmaxf(red[threadIdx.x], red[threadIdx.x + s]);
        __syncthreads();
    }
    if (threadIdx.x == 0) flag[0] = (red[0] > 1e6f) ? 1 : 0;
}

// ---------------- convert all 21 inputs to f32 workspace ----------------
struct InPtrs { const void* p[21]; };

__global__ void cvt_all_kernel(InPtrs in, float* ws, const int* flag) {
    const int sizes[21] = {6000, 96, 16, 512, 32, 4096, 64, 8192, 128,
                           65536, 256, 131072, 512, 172032, 256, 32768, 128,
                           49152, 128, 128, 1};
    const int offs[21] = {OFF_POS, OFF_C1W1, OFF_C1B1, OFF_C1W2, OFF_C1B2,
                          OFF_C2W1, OFF_C2B1, OFF_C2W2, OFF_C2B2,
                          OFF_C3W1, OFF_C3B1, OFF_C3W2, OFF_C3B2,
                          OFF_SMW1, OFF_SMB1, OFF_SMW2, OFF_SMB2,
                          OFF_ECW1, OFF_ECB1, OFF_ECW2, OFF_ECB2};
    int which = blockIdx.y;
    int n = sizes[which];
    int t = blockIdx.x * 256 + threadIdx.x;
    if (t >= n) return;
    float v;
    if (flag[0]) v = ((const float*)in.p[which])[t];
    else v = b2f(((const bf16*)in.p[which])[t]);
    ws[offs[which] + t] = v;
}

// ---------------- kNN: block per (b,i), 256 threads ----------------
template <int C>
__global__ void knn_kernel(const float* __restrict__ x, int* __restrict__ nidx) {
    int bi = blockIdx.x;
    int b = bi / NP;
    __shared__ __align__(16) float xi[(C + 3) & ~3];
    __shared__ float dist[NPAD];
    __shared__ float rv[256];
    __shared__ int ri[256];
    int tid = threadIdx.x;
    for (int c = tid; c < C; c += 256) xi[c] = x[(size_t)bi * C + c];
    __syncthreads();
    for (int j = tid; j < NPAD; j += 256) {
        float s = INFINITY;
        if (j < NP) {
            s = 0.f;
            const float* xj = x + ((size_t)b * NP + j) * C;
            if (C % 4 == 0) {
                for (int c = 0; c < C; c += 4) {
                    float4 a = *(const float4*)(xi + c);
                    float4 q = *(const float4*)(xj + c);
                    float d0 = a.x - q.x, d1 = a.y - q.y, d2 = a.z - q.z, d3 = a.w - q.w;
                    s += d0 * d0 + d1 * d1 + d2 * d2 + d3 * d3;
                }
            } else {
                for (int c = 0; c < C; ++c) { float d = xi[c] - xj[c]; s += d * d; }
            }
        }
        dist[j] = s;
    }
    __syncthreads();
    for (int r = 0; r < KNN; ++r) {
        float bv = INFINITY; int bj = NPAD;
        for (int j = tid; j < NPAD; j += 256) {
            float v = dist[j];
            if (v < bv) { bv = v; bj = j; }
        }
        rv[tid] = bv; ri[tid] = bj;
        __syncthreads();
        for (int s = 128; s > 0; s >>= 1) {
            if (tid < s) {
                float ov = rv[tid + s]; int oj = ri[tid + s];
                if (ov < rv[tid] || (ov == rv[tid] && oj < ri[tid])) { rv[tid] = ov; ri[tid] = oj; }
            }
            __syncthreads();
        }
        if (tid == 0) {
            nidx[bi * KNN + r] = ri[0];
            dist[ri[0]] = INFINITY;
        }
        __syncthreads();
    }
}

// ---------------- fused EdgeConv: block per (b,i) ----------------
template <int CIN, int CHID, int COUT>
__global__ void edgeconv_kernel(const float* __restrict__ x, const int* __restrict__ nidx,
                                const float* __restrict__ w1, const float* __restrict__ b1,
                                const float* __restrict__ w2, const float* __restrict__ b2,
                                float* __restrict__ y) {
    int bi = blockIdx.x;
    int b = bi / NP;
    __shared__ float xi[CIN];
    __shared__ float dx[KNN][CIN];
    __shared__ __align__(16) float hid[CHID][12];
    __shared__ int nb[KNN];
    int tid = threadIdx.x;
    if (tid < KNN) nb[tid] = nidx[bi * KNN + tid];
    for (int c = tid; c < CIN; c += 256) xi[c] = x[(size_t)bi * CIN + c];
    __syncthreads();
    for (int t = tid; t < KNN * CIN; t += 256) {
        int k = t / CIN, c = t % CIN;
        dx[k][c] = x[((size_t)b * NP + nb[k]) * CIN + c] - xi[c];
    }
    __syncthreads();
    for (int h = tid; h < CHID; h += 256) {
        float common = b1[h];
        for (int c = 0; c < CIN; ++c) common += xi[c] * w1[c * CHID + h];
        float acc[KNN];
        for (int k = 0; k < KNN; ++k) acc[k] = common;
        for (int c = 0; c < CIN; ++c) {
            float wv = w1[(CIN + c) * CHID + h];
            for (int k = 0; k < KNN; ++k) acc[k] += dx[k][c] * wv;
        }
        for (int k = 0; k < KNN; ++k) hid[h][k] = fmaxf(acc[k], 0.f);
    }
    __syncthreads();
    for (int o = tid; o < COUT; o += 256) {
        float acc[KNN];
        for (int k = 0; k < KNN; ++k) acc[k] = 0.f;
        for (int h = 0; h < CHID; ++h) {
            float wv = w2[h * COUT + o];
            float4 h0 = *(const float4*)&hid[h][0];
            float4 h1 = *(const float4*)&hid[h][4];
            acc[0] += h0.x * wv; acc[1] += h0.y * wv; acc[2] += h0.z * wv; acc[3] += h0.w * wv;
            acc[4] += h1.x * wv; acc[5] += h1.y * wv; acc[6] += h1.z * wv; acc[7] += h1.w * wv;
        }
        float m = acc[0];
        for (int k = 1; k < KNN; ++k) m = fmaxf(m, acc[k]);
        y[(size_t)bi * COUT + o] = m + b2[o];
    }
}

// ---------------- shared MLP on concat[x1,x2,x3]: 672->256 relu ->128 ----------------
__global__ void sm_kernel(const float* __restrict__ x1, const float* __restrict__ x2,
                          const float* __restrict__ x3,
                          const float* __restrict__ w1, const float* __restrict__ b1,
                          const float* __restrict__ w2, const float* __restrict__ b2,
                          float* __restrict__ sf) {
    int p0 = blockIdx.x * 8;
    __shared__ float in[8][672];
    __shared__ __align__(16) float hid[256][12];
    int tid = threadIdx.x;
    for (int t = tid; t < 8 * 672; t += 256) {
        int k = t / 672, c = t % 672;
        int p = p0 + k;
        float v;
        if (c < 32) v = x1[(size_t)p * 32 + c];
        else if (c < 160) v = x2[(size_t)p * 128 + (c - 32)];
        else v = x3[(size_t)p * 512 + (c - 160)];
        in[k][c] = v;
    }
    __syncthreads();
    {
        int h = tid;
        float acc[8];
        float bb = b1[h];
        for (int k = 0; k < 8; ++k) acc[k] = bb;
        for (int c = 0; c < 672; ++c) {
            float wv = w1[c * 256 + h];
            for (int k = 0; k < 8; ++k) acc[k] += in[k][c] * wv;
        }
        for (int k = 0; k < 8; ++k) hid[h][k] = fmaxf(acc[k], 0.f);
    }
    __syncthreads();
    if (tid < 128) {
        int o = tid;
        float acc[8];
        float bb = b2[o];
        for (int k = 0; k < 8; ++k) acc[k] = bb;
        for (int h = 0; h < 256; ++h) {
            float wv = w2[h * 128 + o];
            float4 h0 = *(const float4*)&hid[h][0];
            float4 h1 = *(const float4*)&hid[h][4];
            acc[0] += h0.x * wv; acc[1] += h0.y * wv; acc[2] += h0.z * wv; acc[3] += h0.w * wv;
            acc[4] += h1.x * wv; acc[5] += h1.y * wv; acc[6] += h1.z * wv; acc[7] += h1.w * wv;
        }
        for (int k = 0; k < 8; ++k) sf[((size_t)p0 + k) * 128 + o] = acc[k];
    }
}

// ---------------- global max pool over N ----------------
__global__ void gmax_kernel(const float* __restrict__ sf, float* __restrict__ g) {
    int b = blockIdx.x, o = threadIdx.x;  // 128 threads
    float m = -INFINITY;
    for (int n = 0; n < NP; ++n) m = fmaxf(m, sf[((size_t)b * NP + n) * 128 + o]);
    g[b * 128 + o] = m;
}

// ---------------- hi = sf @ W[:128], hj = sf @ W[128:256] ----------------
__global__ void hij_kernel(const float* __restrict__ sf, const float* __restrict__ w1,
                           float* __restrict__ hi, float* __restrict__ hj) {
    int p0 = blockIdx.x * 8;
    __shared__ float in[8][128];
    int tid = threadIdx.x;
    for (int t = tid; t < 8 * 128; t += 256) in[t >> 7][t & 127] = sf[(size_t)p0 * 128 + t];
    __syncthreads();
    int sel = tid >> 7, o = tid & 127;
    float acc[8];
    for (int k = 0; k < 8; ++k) acc[k] = 0.f;
    for (int c = 0; c < 128; ++c) {
        float wv = w1[(sel * 128 + c) * 128 + o];
        for (int k = 0; k < 8; ++k) acc[k] += in[k][c] * wv;
    }
    float* dst = sel ? hj : hi;
    for (int k = 0; k < 8; ++k) dst[((size_t)p0 + k) * 128 + o] = acc[k];
}

// ---------------- hg = g @ W[256:384] + b1 ----------------
__global__ void hg_kernel(const float* __restrict__ g, const float* __restrict__ w1,
                          const float* __restrict__ b1, float* __restrict__ hg) {
    int b = blockIdx.x, o = threadIdx.x;  // 128 threads
    float acc = b1[o];
    for (int c = 0; c < 128; ++c) acc += g[b * 128 + c] * w1[(256 + c) * 128 + o];
    hg[b * 128 + o] = acc;
}

// ---------------- pairwise scorer over 32x32 tiles of (i,j), i<j ----------------
__global__ void pair_kernel(const float* __restrict__ hi, const float* __restrict__ hj,
                            const float* __restrict__ hg,
                            const float* __restrict__ w2, const float* __restrict__ b2,
                            void* __restrict__ out, const int* __restrict__ flag) {
    int j0 = blockIdx.x * 32, i0 = blockIdx.y * 32, b = blockIdx.z;
    if (j0 + 31 <= i0) return;
    __shared__ float hit[32][129];
    __shared__ float hjt[32][129];
    __shared__ float hgs[128];
    __shared__ float w2s[128];
    int tid = threadIdx.x;
    if (tid < 128) {
        hgs[tid] = hg[b * 128 + tid];
        w2s[tid] = w2[tid];
    }
    for (int t = tid; t < 32 * 128; t += 256) {
        int r = t >> 7, c = t & 127;
        int i = i0 + r, j = j0 + r;
        hit[r][c] = (i < NP) ? hi[((size_t)b * NP + i) * 128 + c] : 0.f;
        hjt[r][c] = (j < NP) ? hj[((size_t)b * NP + j) * 128 + c] : 0.f;
    }
    __syncthreads();
    float bb = b2[0];
    int f = flag[0];
    int tj = tid & 31;
    int ti0 = tid >> 5;
    int j = j0 + tj;
    float acc[4] = {0.f, 0.f, 0.f, 0.f};
    for (int o = 0; o < 128; ++o) {
        float hv = hjt[tj][o] + hgs[o];
        float wv = w2s[o];
        acc[0] += fmaxf(hit[ti0][o] + hv, 0.f) * wv;
        acc[1] += fmaxf(hit[ti0 + 8][o] + hv, 0.f) * wv;
        acc[2] += fmaxf(hit[ti0 + 16][o] + hv, 0.f) * wv;
        acc[3] += fmaxf(hit[ti0 + 24][o] + hv, 0.f) * wv;
    }
    for (int r = 0; r < 4; ++r) {
        int i = i0 + ti0 + 8 * r;
        if (i < j && j < NP) {
            size_t p = (size_t)i * (NP - 1) - (size_t)i * (i - 1) / 2 + (j - i - 1);
            float mo = acc[r] + bb;
            float pr = 1.f / (1.f + expf(-mo));
            size_t idx0 = (size_t)b * PPAIR + p;
            size_t idx1 = (size_t)NB * PPAIR + idx0;
            if (f) {
                ((float*)out)[idx0] = pr;
                ((float*)out)[idx1] = mo;
            } else {
                ((bf16*)out)[idx0] = __float2bfloat16(pr);
                ((bf16*)out)[idx1] = __float2bfloat16(mo);
            }
        }
    }
}

extern "C" void kernel_launch(void* const* d_in, const int* in_sizes, int n_in,
                              void* d_out, int out_size, void* d_ws, size_t ws_size,
                              hipStream_t stream) {
    float* ws = (float*)d_ws;
    float* posf = ws + OFF_POS;
    float* x1   = ws + OFF_X1;
    float* x2   = ws + OFF_X2;
    float* x3   = ws + OFF_X3;
    float* sf   = ws + OFF_SF;
    float* g    = ws + OFF_G;
    float* hi   = ws + OFF_HI;
    float* hj   = ws + OFF_HJ;
    float* hgb  = ws + OFF_HG;
    int*   flag = (int*)(ws + OFF_FLAG);
    int*   nidx = (int*)(ws + OFF_NIDX);

    // 1) detect input dtype (bf16 vs f32) on-device
    detect_kernel<<<1, 256, 0, stream>>>(d_in[0], flag);

    // 2) convert all inputs to f32 workspace
    InPtrs ip;
    for (int i = 0; i < 21; ++i) ip.p[i] = d_in[i];
    dim3 cgrid(672, 21);
    cvt_all_kernel<<<cgrid, 256, 0, stream>>>(ip, ws, flag);

    // 3) EdgeConv 1 (C=3 -> 32)
    knn_kernel<3><<<NB * NP, 256, 0, stream>>>(posf, nidx);
    edgeconv_kernel<3, 16, 32><<<NB * NP, 256, 0, stream>>>(
        posf, nidx, ws + OFF_C1W1, ws + OFF_C1B1, ws + OFF_C1W2, ws + OFF_C1B2, x1);

    // 4) EdgeConv 2 (C=32 -> 128)
    knn_kernel<32><<<NB * NP, 256, 0, stream>>>(x1, nidx);
    edgeconv_kernel<32, 64, 128><<<NB * NP, 256, 0, stream>>>(
        x1, nidx, ws + OFF_C2W1, ws + OFF_C2B1, ws + OFF_C2W2, ws + OFF_C2B2, x2);

    // 5) EdgeConv 3 (C=128 -> 512)
    knn_kernel<128><<<NB * NP, 256, 0, stream>>>(x2, nidx);
    edgeconv_kernel<128, 256, 512><<<NB * NP, 256, 0, stream>>>(
        x2, nidx, ws + OFF_C3W1, ws + OFF_C3B1, ws + OFF_C3W2, ws + OFF_C3B2, x3);

    // 6) shared MLP -> sf
    sm_kernel<<<NB * NP / 8, 256, 0, stream>>>(
        x1, x2, x3, ws + OFF_SMW1, ws + OFF_SMB1, ws + OFF_SMW2, ws + OFF_SMB2, sf);

    // 7) global max pool
    gmax_kernel<<<NB, 128, 0, stream>>>(sf, g);

    // 8) pair-feature projections
    hij_kernel<<<NB * NP / 8, 256, 0, stream>>>(sf, ws + OFF_ECW1, hi, hj);
    hg_kernel<<<NB, 128, 0, stream>>>(g, ws + OFF_ECW1, ws + OFF_ECB1, hgb);

    // 9) pairwise scorer
    dim3 pgrid(32, 32, NB);
    pair_kernel<<<pgrid, 256, 0, stream>>>(hi, hj, hgb, ws + OFF_ECW2, ws + OFF_ECB2,
                                           d_out, flag);
}

// Round 3
// 677.274 us; speedup vs baseline: 1.0628x; 1.0628x over previous
//
#include <hip/hip_runtime.h>
#include <hip/hip_bf16.h>
#include <cmath>

// Problem constants (B=2, N=1000, k=8 from reference)
#define NB 2
#define NP 1000
#define KNN 8
#define PPAIR 499500  // N*(N-1)/2

typedef __hip_bfloat16 bf16;
typedef unsigned long long u64;

__device__ __forceinline__ float b2f(bf16 v) { return __bfloat162float(v); }

// Workspace layout (float offsets), all 16B-aligned
#define OFF_POS    0
#define OFF_C1W1   6000
#define OFF_C1B1   6096
#define OFF_C1W2   6112
#define OFF_C1B2   6624
#define OFF_C2W1   6656
#define OFF_C2B1   10752
#define OFF_C2W2   10816
#define OFF_C2B2   19008
#define OFF_C3W1   19136
#define OFF_C3B1   84672
#define OFF_C3W2   84928
#define OFF_C3B2   216000
#define OFF_SMW1   216512
#define OFF_SMB1   388544
#define OFF_SMW2   388800
#define OFF_SMB2   421568
#define OFF_ECW1   421696
#define OFF_ECB1   470848
#define OFF_ECW2   470976
#define OFF_ECB2   471104
#define OFF_X1     471112
#define OFF_X2     535112
#define OFF_X3     791112
#define OFF_SF     1815112
#define OFF_G      2071112
#define OFF_HI     2071368
#define OFF_HJ     2327368
#define OFF_HG     2583368
#define OFF_FLAG   2583624   // int
#define OFF_NIDX   2583632   // 16000 ints

// ---------------- dtype detection ----------------
__global__ void detect_kernel(const void* pos, int* flag) {
    __shared__ float red[256];
    const unsigned short* p = (const unsigned short*)pos;
    float m = 0.f;
    for (int t = threadIdx.x; t < 6000; t += 256) {
        unsigned int u = ((unsigned int)p[t]) << 16;
        float v = fabsf(__uint_as_float(u));
        if (!isfinite(v)) v = 1e30f;
        m = fmaxf(m, v);
    }
    red[threadIdx.x] = m;
    __syncthreads();
    for (int s = 128; s > 0; s >>= 1) {
        if (threadIdx.x < s) red[threadIdx.x] = fmaxf(red[threadIdx.x], red[threadIdx.x + s]);
        __syncthreads();
    }
    if (threadIdx.x == 0) flag[0] = (red[0] > 1e6f) ? 1 : 0;
}

// ---------------- convert all 21 inputs to f32 workspace ----------------
struct InPtrs { const void* p[21]; };

__global__ void cvt_all_kernel(InPtrs in, float* ws, const int* flag) {
    const int sizes[21] = {6000, 96, 16, 512, 32, 4096, 64, 8192, 128,
                           65536, 256, 131072, 512, 172032, 256, 32768, 128,
                           49152, 128, 128, 1};
    const int offs[21] = {OFF_POS, OFF_C1W1, OFF_C1B1, OFF_C1W2, OFF_C1B2,
                          OFF_C2W1, OFF_C2B1, OFF_C2W2, OFF_C2B2,
                          OFF_C3W1, OFF_C3B1, OFF_C3W2, OFF_C3B2,
                          OFF_SMW1, OFF_SMB1, OFF_SMW2, OFF_SMB2,
                          OFF_ECW1, OFF_ECB1, OFF_ECW2, OFF_ECB2};
    int which = blockIdx.y;
    int n = sizes[which];
    int t = blockIdx.x * 256 + threadIdx.x;
    if (t >= n) return;
    float v;
    if (flag[0]) v = ((const float*)in.p[which])[t];
    else v = b2f(((const bf16*)in.p[which])[t]);
    ws[offs[which] + t] = v;
}

// ---------------- kNN: wave per query, barrier-free top-8 ----------------
// Per lane: scan ~16 candidates keeping sorted top-8 as packed u64
// (float_bits(d2)<<32 | j) -> lexicographic (d2, j) order == jax top_k ties.
// Then 6-stage shfl_xor bitonic merge across the wave.
__device__ __forceinline__ void ce(u64& a, u64& b) {
    u64 lo = a < b ? a : b;
    u64 hi = a < b ? b : a;
    a = lo; b = hi;
}

template <int C>
__global__ void knn_kernel(const float* __restrict__ x, int* __restrict__ nidx) {
    constexpr int CP = (C + 3) & ~3;
    __shared__ __align__(16) float xi[4][CP];
    int lane = threadIdx.x & 63;
    int wave = threadIdx.x >> 6;
    int bi = blockIdx.x * 4 + wave;        // query index, < NB*NP (2000 divisible by 4)
    int b = bi / NP;
    // stage this wave's query point into LDS
    for (int c = lane; c < C; c += 64) xi[wave][c] = x[(size_t)bi * C + c];
    __syncthreads();

    u64 best[KNN];
    for (int r = 0; r < KNN; ++r) best[r] = ~0ull;

    for (int j = lane; j < 1024; j += 64) {   // 16 iterations
        u64 cand;
        if (j < NP) {
            float s = 0.f;
            const float* xj = x + ((size_t)b * NP + j) * C;
            if (C % 4 == 0) {
                #pragma unroll
                for (int c = 0; c < C; c += 4) {
                    float4 a = *(const float4*)(&xi[wave][c]);
                    float4 q = *(const float4*)(xj + c);
                    float d0 = a.x - q.x, d1 = a.y - q.y, d2 = a.z - q.z, d3 = a.w - q.w;
                    s += d0 * d0 + d1 * d1 + d2 * d2 + d3 * d3;
                }
            } else {
                #pragma unroll
                for (int c = 0; c < C; ++c) { float d = xi[wave][c] - xj[c]; s += d * d; }
            }
            cand = (((u64)__float_as_uint(s)) << 32) | (unsigned)j;
        } else {
            cand = ~0ull;
        }
        // branchless sorted insert (drop largest)
        u64 cur = cand;
        #pragma unroll
        for (int r = 0; r < KNN; ++r) {
            u64 lo = best[r] < cur ? best[r] : cur;
            u64 hi = best[r] < cur ? cur : best[r];
            best[r] = lo; cur = hi;
        }
    }

    // butterfly merge of sorted 8-lists across 64 lanes
    #pragma unroll
    for (int m = 1; m < 64; m <<= 1) {
        u64 other[KNN];
        #pragma unroll
        for (int r = 0; r < KNN; ++r)
            other[r] = __shfl_xor((unsigned long long)best[r], m, 64);
        // bitonic half-merge: 8 smallest of A ∪ B (bitonic sequence)
        u64 v[KNN];
        #pragma unroll
        for (int r = 0; r < KNN; ++r)
            v[r] = best[r] < other[7 - r] ? best[r] : other[7 - r];
        // half-cleaner network -> ascending
        ce(v[0], v[4]); ce(v[1], v[5]); ce(v[2], v[6]); ce(v[3], v[7]);
        ce(v[0], v[2]); ce(v[1], v[3]); ce(v[4], v[6]); ce(v[5], v[7]);
        ce(v[0], v[1]); ce(v[2], v[3]); ce(v[4], v[5]); ce(v[6], v[7]);
        #pragma unroll
        for (int r = 0; r < KNN; ++r) best[r] = v[r];
    }

    if (lane < KNN) nidx[bi * KNN + lane] = (int)(best[lane] & 0xffffffffu);
}

// ---------------- fused EdgeConv: block per (b,i) ----------------
template <int CIN, int CHID, int COUT>
__global__ void edgeconv_kernel(const float* __restrict__ x, const int* __restrict__ nidx,
                                const float* __restrict__ w1, const float* __restrict__ b1,
                                const float* __restrict__ w2, const float* __restrict__ b2,
                                float* __restrict__ y) {
    int bi = blockIdx.x;
    int b = bi / NP;
    __shared__ float xi[CIN];
    __shared__ float dx[KNN][CIN];
    __shared__ __align__(16) float hid[CHID][12];
    __shared__ int nb[KNN];
    int tid = threadIdx.x;
    if (tid < KNN) nb[tid] = nidx[bi * KNN + tid];
    for (int c = tid; c < CIN; c += 256) xi[c] = x[(size_t)bi * CIN + c];
    __syncthreads();
    for (int t = tid; t < KNN * CIN; t += 256) {
        int k = t / CIN, c = t % CIN;
        dx[k][c] = x[((size_t)b * NP + nb[k]) * CIN + c] - xi[c];
    }
    __syncthreads();
    for (int h = tid; h < CHID; h += 256) {
        float common = b1[h];
        for (int c = 0; c < CIN; ++c) common += xi[c] * w1[c * CHID + h];
        float acc[KNN];
        for (int k = 0; k < KNN; ++k) acc[k] = common;
        for (int c = 0; c < CIN; ++c) {
            float wv = w1[(CIN + c) * CHID + h];
            for (int k = 0; k < KNN; ++k) acc[k] += dx[k][c] * wv;
        }
        for (int k = 0; k < KNN; ++k) hid[h][k] = fmaxf(acc[k], 0.f);
    }
    __syncthreads();
    for (int o = tid; o < COUT; o += 256) {
        float acc[KNN];
        for (int k = 0; k < KNN; ++k) acc[k] = 0.f;
        for (int h = 0; h < CHID; ++h) {
            float wv = w2[h * COUT + o];
            float4 h0 = *(const float4*)&hid[h][0];
            float4 h1 = *(const float4*)&hid[h][4];
            acc[0] += h0.x * wv; acc[1] += h0.y * wv; acc[2] += h0.z * wv; acc[3] += h0.w * wv;
            acc[4] += h1.x * wv; acc[5] += h1.y * wv; acc[6] += h1.z * wv; acc[7] += h1.w * wv;
        }
        float m = acc[0];
        for (int k = 1; k < KNN; ++k) m = fmaxf(m, acc[k]);
        y[(size_t)bi * COUT + o] = m + b2[o];
    }
}

// ---------------- shared MLP on concat[x1,x2,x3]: 672->256 relu ->128 ----------------
__global__ void sm_kernel(const float* __restrict__ x1, const float* __restrict__ x2,
                          const float* __restrict__ x3,
                          const float* __restrict__ w1, const float* __restrict__ b1,
                          const float* __restrict__ w2, const float* __restrict__ b2,
                          float* __restrict__ sf) {
    int p0 = blockIdx.x * 8;
    __shared__ float in[8][672];
    __shared__ __align__(16) float hid[256][12];
    int tid = threadIdx.x;
    for (int t = tid; t < 8 * 672; t += 256) {
        int k = t / 672, c = t % 672;
        int p = p0 + k;
        float v;
        if (c < 32) v = x1[(size_t)p * 32 + c];
        else if (c < 160) v = x2[(size_t)p * 128 + (c - 32)];
        else v = x3[(size_t)p * 512 + (c - 160)];
        in[k][c] = v;
    }
    __syncthreads();
    {
        int h = tid;
        float acc[8];
        float bb = b1[h];
        for (int k = 0; k < 8; ++k) acc[k] = bb;
        for (int c = 0; c < 672; ++c) {
            float wv = w1[c * 256 + h];
            for (int k = 0; k < 8; ++k) acc[k] += in[k][c] * wv;
        }
        for (int k = 0; k < 8; ++k) hid[h][k] = fmaxf(acc[k], 0.f);
    }
    __syncthreads();
    if (tid < 128) {
        int o = tid;
        float acc[8];
        float bb = b2[o];
        for (int k = 0; k < 8; ++k) acc[k] = bb;
        for (int h = 0; h < 256; ++h) {
            float wv = w2[h * 128 + o];
            float4 h0 = *(const float4*)&hid[h][0];
            float4 h1 = *(const float4*)&hid[h][4];
            acc[0] += h0.x * wv; acc[1] += h0.y * wv; acc[2] += h0.z * wv; acc[3] += h0.w * wv;
            acc[4] += h1.x * wv; acc[5] += h1.y * wv; acc[6] += h1.z * wv; acc[7] += h1.w * wv;
        }
        for (int k = 0; k < 8; ++k) sf[((size_t)p0 + k) * 128 + o] = acc[k];
    }
}

// ---------------- global max pool over N ----------------
__global__ void gmax_kernel(const float* __restrict__ sf, float* __restrict__ g) {
    int b = blockIdx.x, o = threadIdx.x;  // 128 threads
    float m = -INFINITY;
    for (int n = 0; n < NP; ++n) m = fmaxf(m, sf[((size_t)b * NP + n) * 128 + o]);
    g[b * 128 + o] = m;
}

// ---------------- hi = sf @ W[:128], hj = sf @ W[128:256] ----------------
__global__ void hij_kernel(const float* __restrict__ sf, const float* __restrict__ w1,
                           float* __restrict__ hi, float* __restrict__ hj) {
    int p0 = blockIdx.x * 8;
    __shared__ float in[8][128];
    int tid = threadIdx.x;
    for (int t = tid; t < 8 * 128; t += 256) in[t >> 7][t & 127] = sf[(size_t)p0 * 128 + t];
    __syncthreads();
    int sel = tid >> 7, o = tid & 127;
    float acc[8];
    for (int k = 0; k < 8; ++k) acc[k] = 0.f;
    for (int c = 0; c < 128; ++c) {
        float wv = w1[(sel * 128 + c) * 128 + o];
        for (int k = 0; k < 8; ++k) acc[k] += in[k][c] * wv;
    }
    float* dst = sel ? hj : hi;
    for (int k = 0; k < 8; ++k) dst[((size_t)p0 + k) * 128 + o] = acc[k];
}

// ---------------- hg = g @ W[256:384] + b1 ----------------
__global__ void hg_kernel(const float* __restrict__ g, const float* __restrict__ w1,
                          const float* __restrict__ b1, float* __restrict__ hg) {
    int b = blockIdx.x, o = threadIdx.x;  // 128 threads
    float acc = b1[o];
    for (int c = 0; c < 128; ++c) acc += g[b * 128 + c] * w1[(256 + c) * 128 + o];
    hg[b * 128 + o] = acc;
}

// ---------------- pairwise scorer over 32x32 tiles of (i,j), i<j ----------------
__global__ void pair_kernel(const float* __restrict__ hi, const float* __restrict__ hj,
                            const float* __restrict__ hg,
                            const float* __restrict__ w2, const float* __restrict__ b2,
                            void* __restrict__ out, const int* __restrict__ flag) {
    int j0 = blockIdx.x * 32, i0 = blockIdx.y * 32, b = blockIdx.z;
    if (j0 + 31 <= i0) return;
    __shared__ float hit[32][129];
    __shared__ float hjt[32][129];
    __shared__ float hgs[128];
    __shared__ float w2s[128];
    int tid = threadIdx.x;
    if (tid < 128) {
        hgs[tid] = hg[b * 128 + tid];
        w2s[tid] = w2[tid];
    }
    for (int t = tid; t < 32 * 128; t += 256) {
        int r = t >> 7, c = t & 127;
        int i = i0 + r, j = j0 + r;
        hit[r][c] = (i < NP) ? hi[((size_t)b * NP + i) * 128 + c] : 0.f;
        hjt[r][c] = (j < NP) ? hj[((size_t)b * NP + j) * 128 + c] : 0.f;
    }
    __syncthreads();
    float bb = b2[0];
    int f = flag[0];
    int tj = tid & 31;
    int ti0 = tid >> 5;
    int j = j0 + tj;
    float acc[4] = {0.f, 0.f, 0.f, 0.f};
    for (int o = 0; o < 128; ++o) {
        float hv = hjt[tj][o] + hgs[o];
        float wv = w2s[o];
        acc[0] += fmaxf(hit[ti0][o] + hv, 0.f) * wv;
        acc[1] += fmaxf(hit[ti0 + 8][o] + hv, 0.f) * wv;
        acc[2] += fmaxf(hit[ti0 + 16][o] + hv, 0.f) * wv;
        acc[3] += fmaxf(hit[ti0 + 24][o] + hv, 0.f) * wv;
    }
    for (int r = 0; r < 4; ++r) {
        int i = i0 + ti0 + 8 * r;
        if (i < j && j < NP) {
            size_t p = (size_t)i * (NP - 1) - (size_t)i * (i - 1) / 2 + (j - i - 1);
            float mo = acc[r] + bb;
            float pr = 1.f / (1.f + expf(-mo));
            size_t idx0 = (size_t)b * PPAIR + p;
            size_t idx1 = (size_t)NB * PPAIR + idx0;
            if (f) {
                ((float*)out)[idx0] = pr;
                ((float*)out)[idx1] = mo;
            } else {
                ((bf16*)out)[idx0] = __float2bfloat16(pr);
                ((bf16*)out)[idx1] = __float2bfloat16(mo);
            }
        }
    }
}

extern "C" void kernel_launch(void* const* d_in, const int* in_sizes, int n_in,
                              void* d_out, int out_size, void* d_ws, size_t ws_size,
                              hipStream_t stream) {
    float* ws = (float*)d_ws;
    float* posf = ws + OFF_POS;
    float* x1   = ws + OFF_X1;
    float* x2   = ws + OFF_X2;
    float* x3   = ws + OFF_X3;
    float* sf   = ws + OFF_SF;
    float* g    = ws + OFF_G;
    float* hi   = ws + OFF_HI;
    float* hj   = ws + OFF_HJ;
    float* hgb  = ws + OFF_HG;
    int*   flag = (int*)(ws + OFF_FLAG);
    int*   nidx = (int*)(ws + OFF_NIDX);

    // 1) detect input dtype (bf16 vs f32) on-device
    detect_kernel<<<1, 256, 0, stream>>>(d_in[0], flag);

    // 2) convert all inputs to f32 workspace
    InPtrs ip;
    for (int i = 0; i < 21; ++i) ip.p[i] = d_in[i];
    dim3 cgrid(672, 21);
    cvt_all_kernel<<<cgrid, 256, 0, stream>>>(ip, ws, flag);

    // 3) EdgeConv 1 (C=3 -> 32)
    knn_kernel<3><<<NB * NP / 4, 256, 0, stream>>>(posf, nidx);
    edgeconv_kernel<3, 16, 32><<<NB * NP, 256, 0, stream>>>(
        posf, nidx, ws + OFF_C1W1, ws + OFF_C1B1, ws + OFF_C1W2, ws + OFF_C1B2, x1);

    // 4) EdgeConv 2 (C=32 -> 128)
    knn_kernel<32><<<NB * NP / 4, 256, 0, stream>>>(x1, nidx);
    edgeconv_kernel<32, 64, 128><<<NB * NP, 256, 0, stream>>>(
        x1, nidx, ws + OFF_C2W1, ws + OFF_C2B1, ws + OFF_C2W2, ws + OFF_C2B2, x2);

    // 5) EdgeConv 3 (C=128 -> 512)
    knn_kernel<128><<<NB * NP / 4, 256, 0, stream>>>(x2, nidx);
    edgeconv_kernel<128, 256, 512><<<NB * NP, 256, 0, stream>>>(
        x2, nidx, ws + OFF_C3W1, ws + OFF_C3B1, ws + OFF_C3W2, ws + OFF_C3B2, x3);

    // 6) shared MLP -> sf
    sm_kernel<<<NB * NP / 8, 256, 0, stream>>>(
        x1, x2, x3, ws + OFF_SMW1, ws + OFF_SMB1, ws + OFF_SMW2, ws + OFF_SMB2, sf);

    // 7) global max pool
    gmax_kernel<<<NB, 128, 0, stream>>>(sf, g);

    // 8) pair-feature projections
    hij_kernel<<<NB * NP / 8, 256, 0, stream>>>(sf, ws + OFF_ECW1, hi, hj);
    hg_kernel<<<NB, 128, 0, stream>>>(g, ws + OFF_ECW1, ws + OFF_ECB1, hgb);

    // 9) pairwise scorer
    dim3 pgrid(32, 32, NB);
    pair_kernel<<<pgrid, 256, 0, stream>>>(hi, hj, hgb, ws + OFF_ECW2, ws + OFF_ECB2,
                                           d_out, flag);
}

// Round 4
// 544.136 us; speedup vs baseline: 1.3229x; 1.2447x over previous
//
#include <hip/hip_runtime.h>
#include <hip/hip_bf16.h>
#include <cmath>

// Problem constants (B=2, N=1000, k=8 from reference)
#define NB 2
#define NP 1000
#define KNN 8
#define PPAIR 499500  // N*(N-1)/2

typedef __hip_bfloat16 bf16;
typedef unsigned long long u64;

__device__ __forceinline__ float b2f(bf16 v) { return __bfloat162float(v); }

// Workspace layout (float offsets), all 16B-aligned
#define OFF_POS    0
#define OFF_C1W1   6000
#define OFF_C1B1   6096
#define OFF_C1W2   6112
#define OFF_C1B2   6624
#define OFF_C2W1   6656
#define OFF_C2B1   10752
#define OFF_C2W2   10816
#define OFF_C2B2   19008
#define OFF_C3W1   19136
#define OFF_C3B1   84672
#define OFF_C3W2   84928
#define OFF_C3B2   216000
#define OFF_SMW1   216512
#define OFF_SMB1   388544
#define OFF_SMW2   388800
#define OFF_SMB2   421568
#define OFF_ECW1   421696
#define OFF_ECB1   470848
#define OFF_ECW2   470976
#define OFF_ECB2   471104
#define OFF_X1     471112
#define OFF_X2     535112
#define OFF_X3     791112
#define OFF_SF     1815112
#define OFF_G      2071112
#define OFF_HI     2071368
#define OFF_HJ     2327368
#define OFF_HG     2583368
#define OFF_FLAG   2583624   // int
#define OFF_NIDX   2583632   // 16000 ints
#define OFF_D2     2599632   // 1000*1024 f32, reused per batch & per layer
#define OFF_GP     3623632   // 50*128 partial max

// ---------------- dtype detection ----------------
__global__ void detect_kernel(const void* pos, int* flag) {
    __shared__ float red[256];
    const unsigned short* p = (const unsigned short*)pos;
    float m = 0.f;
    for (int t = threadIdx.x; t < 6000; t += 256) {
        unsigned int u = ((unsigned int)p[t]) << 16;
        float v = fabsf(__uint_as_float(u));
        if (!isfinite(v)) v = 1e30f;
        m = fmaxf(m, v);
    }
    red[threadIdx.x] = m;
    __syncthreads();
    for (int s = 128; s > 0; s >>= 1) {
        if (threadIdx.x < s) red[threadIdx.x] = fmaxf(red[threadIdx.x], red[threadIdx.x + s]);
        __syncthreads();
    }
    if (threadIdx.x == 0) flag[0] = (red[0] > 1e6f) ? 1 : 0;
}

// ---------------- convert all 21 inputs to f32 workspace ----------------
struct InPtrs { const void* p[21]; };

__global__ void cvt_all_kernel(InPtrs in, float* ws, const int* flag) {
    const int sizes[21] = {6000, 96, 16, 512, 32, 4096, 64, 8192, 128,
                           65536, 256, 131072, 512, 172032, 256, 32768, 128,
                           49152, 128, 128, 1};
    const int offs[21] = {OFF_POS, OFF_C1W1, OFF_C1B1, OFF_C1W2, OFF_C1B2,
                          OFF_C2W1, OFF_C2B1, OFF_C2W2, OFF_C2B2,
                          OFF_C3W1, OFF_C3B1, OFF_C3W2, OFF_C3B2,
                          OFF_SMW1, OFF_SMB1, OFF_SMW2, OFF_SMB2,
                          OFF_ECW1, OFF_ECB1, OFF_ECW2, OFF_ECB2};
    int which = blockIdx.y;
    int n = sizes[which];
    int t = blockIdx.x * 256 + threadIdx.x;
    if (t >= n) return;
    float v;
    if (flag[0]) v = ((const float*)in.p[which])[t];
    else v = b2f(((const bf16*)in.p[which])[t]);
    ws[offs[which] + t] = v;
}

// ---------------- dist: tiled 64x64 squared-distance matrix ----------------
// d2[i*1024+j] = sum_c (x[b,i,c]-x[b,j,c])^2  (diff-squared form; same as
// the R2/R3-verified knn numerics)
template <int C>
__global__ void dist_kernel(const float* __restrict__ x, float* __restrict__ d2, int b) {
    constexpr int CK = (C < 32) ? C : 32;
    constexpr int NCH = (C + CK - 1) / CK;
    __shared__ float As[64][CK + 1];
    __shared__ float Bs[64][CK + 1];
    int tid = threadIdx.x;
    int i0 = blockIdx.y * 64, j0 = blockIdx.x * 64;
    int tx = tid & 15, ty = tid >> 4;   // 16x16 thread grid, 4x4 outputs each
    float acc[4][4];
    #pragma unroll
    for (int r = 0; r < 4; ++r)
        #pragma unroll
        for (int s = 0; s < 4; ++s) acc[r][s] = 0.f;

    for (int ch = 0; ch < NCH; ++ch) {
        int k0 = ch * CK;
        for (int idx = tid; idx < 64 * CK; idx += 256) {
            int row = idx / CK, col = idx % CK;
            int gi = i0 + row, gj = j0 + row;
            As[row][col] = (gi < NP) ? x[((size_t)b * NP + gi) * C + k0 + col] : 0.f;
            Bs[row][col] = (gj < NP) ? x[((size_t)b * NP + gj) * C + k0 + col] : 0.f;
        }
        __syncthreads();
        #pragma unroll
        for (int k = 0; k < CK; ++k) {
            float av[4], bv[4];
            #pragma unroll
            for (int r = 0; r < 4; ++r) av[r] = As[ty * 4 + r][k];
            #pragma unroll
            for (int s = 0; s < 4; ++s) bv[s] = Bs[tx * 4 + s][k];
            #pragma unroll
            for (int r = 0; r < 4; ++r)
                #pragma unroll
                for (int s = 0; s < 4; ++s) {
                    float d = av[r] - bv[s];
                    acc[r][s] += d * d;
                }
        }
        __syncthreads();
    }
    #pragma unroll
    for (int r = 0; r < 4; ++r) {
        int i = i0 + ty * 4 + r;
        if (i < NP) {
            float4 v = make_float4(acc[r][0], acc[r][1], acc[r][2], acc[r][3]);
            *(float4*)(d2 + (size_t)i * 1024 + j0 + tx * 4) = v;
        }
    }
}

// ---------------- select: wave per query, coalesced row scan, top-8 ----------------
__device__ __forceinline__ void ce(u64& a, u64& b) {
    u64 lo = a < b ? a : b;
    u64 hi = a < b ? b : a;
    a = lo; b = hi;
}

__global__ void select_kernel(const float* __restrict__ d2, int* __restrict__ nidx, int b) {
    int lane = threadIdx.x & 63;
    int wave = threadIdx.x >> 6;
    int i = blockIdx.x * 4 + wave;          // query in [0, NP)
    const float* row = d2 + (size_t)i * 1024;

    u64 best[KNN];
    #pragma unroll
    for (int r = 0; r < KNN; ++r) best[r] = ~0ull;

    #pragma unroll
    for (int it = 0; it < 16; ++it) {
        int j = lane + it * 64;
        u64 cand = ~0ull;
        if (j < NP) cand = (((u64)__float_as_uint(row[j])) << 32) | (unsigned)j;
        u64 cur = cand;
        #pragma unroll
        for (int r = 0; r < KNN; ++r) {
            u64 lo = best[r] < cur ? best[r] : cur;
            u64 hi = best[r] < cur ? cur : best[r];
            best[r] = lo; cur = hi;
        }
    }

    #pragma unroll
    for (int m = 1; m < 64; m <<= 1) {
        u64 other[KNN];
        #pragma unroll
        for (int r = 0; r < KNN; ++r)
            other[r] = __shfl_xor((unsigned long long)best[r], m, 64);
        u64 v[KNN];
        #pragma unroll
        for (int r = 0; r < KNN; ++r)
            v[r] = best[r] < other[7 - r] ? best[r] : other[7 - r];
        ce(v[0], v[4]); ce(v[1], v[5]); ce(v[2], v[6]); ce(v[3], v[7]);
        ce(v[0], v[2]); ce(v[1], v[3]); ce(v[4], v[6]); ce(v[5], v[7]);
        ce(v[0], v[1]); ce(v[2], v[3]); ce(v[4], v[5]); ce(v[6], v[7]);
        #pragma unroll
        for (int r = 0; r < KNN; ++r) best[r] = v[r];
    }

    if (lane < KNN) nidx[((size_t)b * NP + i) * KNN + lane] = (int)(best[lane] & 0xffffffffu);
}

// ---------------- fused EdgeConv: block per (b,i) ----------------
template <int CIN, int CHID, int COUT>
__global__ void edgeconv_kernel(const float* __restrict__ x, const int* __restrict__ nidx,
                                const float* __restrict__ w1, const float* __restrict__ b1,
                                const float* __restrict__ w2, const float* __restrict__ b2,
                                float* __restrict__ y) {
    int bi = blockIdx.x;
    int b = bi / NP;
    __shared__ float xi[CIN];
    __shared__ float dx[KNN][CIN];
    __shared__ __align__(16) float hid[CHID][12];
    __shared__ int nb[KNN];
    int tid = threadIdx.x;
    if (tid < KNN) nb[tid] = nidx[bi * KNN + tid];
    for (int c = tid; c < CIN; c += 256) xi[c] = x[(size_t)bi * CIN + c];
    __syncthreads();
    for (int t = tid; t < KNN * CIN; t += 256) {
        int k = t / CIN, c = t % CIN;
        dx[k][c] = x[((size_t)b * NP + nb[k]) * CIN + c] - xi[c];
    }
    __syncthreads();
    for (int h = tid; h < CHID; h += 256) {
        float common = b1[h];
        for (int c = 0; c < CIN; ++c) common += xi[c] * w1[c * CHID + h];
        float acc[KNN];
        for (int k = 0; k < KNN; ++k) acc[k] = common;
        for (int c = 0; c < CIN; ++c) {
            float wv = w1[(CIN + c) * CHID + h];
            for (int k = 0; k < KNN; ++k) acc[k] += dx[k][c] * wv;
        }
        for (int k = 0; k < KNN; ++k) hid[h][k] = fmaxf(acc[k], 0.f);
    }
    __syncthreads();
    for (int o = tid; o < COUT; o += 256) {
        float acc[KNN];
        for (int k = 0; k < KNN; ++k) acc[k] = 0.f;
        for (int h = 0; h < CHID; ++h) {
            float wv = w2[h * COUT + o];
            float4 h0 = *(const float4*)&hid[h][0];
            float4 h1 = *(const float4*)&hid[h][4];
            acc[0] += h0.x * wv; acc[1] += h0.y * wv; acc[2] += h0.z * wv; acc[3] += h0.w * wv;
            acc[4] += h1.x * wv; acc[5] += h1.y * wv; acc[6] += h1.z * wv; acc[7] += h1.w * wv;
        }
        float m = acc[0];
        for (int k = 1; k < KNN; ++k) m = fmaxf(m, acc[k]);
        y[(size_t)bi * COUT + o] = m + b2[o];
    }
}

// ---------------- shared MLP on concat[x1,x2,x3]: 672->256 relu ->128 ----------------
__global__ void sm_kernel(const float* __restrict__ x1, const float* __restrict__ x2,
                          const float* __restrict__ x3,
                          const float* __restrict__ w1, const float* __restrict__ b1,
                          const float* __restrict__ w2, const float* __restrict__ b2,
                          float* __restrict__ sf) {
    int p0 = blockIdx.x * 8;
    __shared__ float in[8][672];
    __shared__ __align__(16) float hid[256][12];
    int tid = threadIdx.x;
    for (int t = tid; t < 8 * 672; t += 256) {
        int k = t / 672, c = t % 672;
        int p = p0 + k;
        float v;
        if (c < 32) v = x1[(size_t)p * 32 + c];
        else if (c < 160) v = x2[(size_t)p * 128 + (c - 32)];
        else v = x3[(size_t)p * 512 + (c - 160)];
        in[k][c] = v;
    }
    __syncthreads();
    {
        int h = tid;
        float acc[8];
        float bb = b1[h];
        for (int k = 0; k < 8; ++k) acc[k] = bb;
        for (int c = 0; c < 672; ++c) {
            float wv = w1[c * 256 + h];
            for (int k = 0; k < 8; ++k) acc[k] += in[k][c] * wv;
        }
        for (int k = 0; k < 8; ++k) hid[h][k] = fmaxf(acc[k], 0.f);
    }
    __syncthreads();
    if (tid < 128) {
        int o = tid;
        float acc[8];
        float bb = b2[o];
        for (int k = 0; k < 8; ++k) acc[k] = bb;
        for (int h = 0; h < 256; ++h) {
            float wv = w2[h * 128 + o];
            float4 h0 = *(const float4*)&hid[h][0];
            float4 h1 = *(const float4*)&hid[h][4];
            acc[0] += h0.x * wv; acc[1] += h0.y * wv; acc[2] += h0.z * wv; acc[3] += h0.w * wv;
            acc[4] += h1.x * wv; acc[5] += h1.y * wv; acc[6] += h1.z * wv; acc[7] += h1.w * wv;
        }
        for (int k = 0; k < 8; ++k) sf[((size_t)p0 + k) * 128 + o] = acc[k];
    }
}

// ---------------- global max pool, two-stage ----------------
__global__ void gmax1_kernel(const float* __restrict__ sf, float* __restrict__ part) {
    int m = blockIdx.x;                 // NB*25 blocks
    int b = m / 25, ch = m % 25, o = threadIdx.x;  // 128 threads
    float v = -INFINITY;
    int n0 = ch * 40;
    for (int n = n0; n < n0 + 40; ++n)
        v = fmaxf(v, sf[((size_t)b * NP + n) * 128 + o]);
    part[(size_t)m * 128 + o] = v;
}

__global__ void gmax2_kernel(const float* __restrict__ part, float* __restrict__ g) {
    int b = blockIdx.x, o = threadIdx.x;  // 128 threads
    float v = -INFINITY;
    for (int ch = 0; ch < 25; ++ch)
        v = fmaxf(v, part[((size_t)b * 25 + ch) * 128 + o]);
    g[b * 128 + o] = v;
}

// ---------------- hi = sf @ W[:128], hj = sf @ W[128:256] ----------------
__global__ void hij_kernel(const float* __restrict__ sf, const float* __restrict__ w1,
                           float* __restrict__ hi, float* __restrict__ hj) {
    int p0 = blockIdx.x * 8;
    __shared__ float in[8][128];
    int tid = threadIdx.x;
    for (int t = tid; t < 8 * 128; t += 256) in[t >> 7][t & 127] = sf[(size_t)p0 * 128 + t];
    __syncthreads();
    int sel = tid >> 7, o = tid & 127;
    float acc[8];
    for (int k = 0; k < 8; ++k) acc[k] = 0.f;
    for (int c = 0; c < 128; ++c) {
        float wv = w1[(sel * 128 + c) * 128 + o];
        for (int k = 0; k < 8; ++k) acc[k] += in[k][c] * wv;
    }
    float* dst = sel ? hj : hi;
    for (int k = 0; k < 8; ++k) dst[((size_t)p0 + k) * 128 + o] = acc[k];
}

// ---------------- hg = g @ W[256:384] + b1 ----------------
__global__ void hg_kernel(const float* __restrict__ g, const float* __restrict__ w1,
                          const float* __restrict__ b1, float* __restrict__ hg) {
    int b = blockIdx.x, o = threadIdx.x;  // 128 threads
    float acc = b1[o];
    for (int c = 0; c < 128; ++c) acc += g[b * 128 + c] * w1[(256 + c) * 128 + o];
    hg[b * 128 + o] = acc;
}

// ---------------- pairwise scorer over 32x32 tiles of (i,j), i<j ----------------
__global__ void pair_kernel(const float* __restrict__ hi, const float* __restrict__ hj,
                            const float* __restrict__ hg,
                            const float* __restrict__ w2, const float* __restrict__ b2,
                            void* __restrict__ out, const int* __restrict__ flag) {
    int j0 = blockIdx.x * 32, i0 = blockIdx.y * 32, b = blockIdx.z;
    if (j0 + 31 <= i0) return;
    __shared__ float hit[32][129];
    __shared__ float hjt[32][129];
    __shared__ float hgs[128];
    __shared__ float w2s[128];
    int tid = threadIdx.x;
    if (tid < 128) {
        hgs[tid] = hg[b * 128 + tid];
        w2s[tid] = w2[tid];
    }
    for (int t = tid; t < 32 * 128; t += 256) {
        int r = t >> 7, c = t & 127;
        int i = i0 + r, j = j0 + r;
        hit[r][c] = (i < NP) ? hi[((size_t)b * NP + i) * 128 + c] : 0.f;
        hjt[r][c] = (j < NP) ? hj[((size_t)b * NP + j) * 128 + c] : 0.f;
    }
    __syncthreads();
    float bb = b2[0];
    int f = flag[0];
    int tj = tid & 31;
    int ti0 = tid >> 5;
    int j = j0 + tj;
    float acc[4] = {0.f, 0.f, 0.f, 0.f};
    for (int o = 0; o < 128; ++o) {
        float hv = hjt[tj][o] + hgs[o];
        float wv = w2s[o];
        acc[0] += fmaxf(hit[ti0][o] + hv, 0.f) * wv;
        acc[1] += fmaxf(hit[ti0 + 8][o] + hv, 0.f) * wv;
        acc[2] += fmaxf(hit[ti0 + 16][o] + hv, 0.f) * wv;
        acc[3] += fmaxf(hit[ti0 + 24][o] + hv, 0.f) * wv;
    }
    for (int r = 0; r < 4; ++r) {
        int i = i0 + ti0 + 8 * r;
        if (i < j && j < NP) {
            size_t p = (size_t)i * (NP - 1) - (size_t)i * (i - 1) / 2 + (j - i - 1);
            float mo = acc[r] + bb;
            float pr = 1.f / (1.f + expf(-mo));
            size_t idx0 = (size_t)b * PPAIR + p;
            size_t idx1 = (size_t)NB * PPAIR + idx0;
            if (f) {
                ((float*)out)[idx0] = pr;
                ((float*)out)[idx1] = mo;
            } else {
                ((bf16*)out)[idx0] = __float2bfloat16(pr);
                ((bf16*)out)[idx1] = __float2bfloat16(mo);
            }
        }
    }
}

extern "C" void kernel_launch(void* const* d_in, const int* in_sizes, int n_in,
                              void* d_out, int out_size, void* d_ws, size_t ws_size,
                              hipStream_t stream) {
    float* ws = (float*)d_ws;
    float* posf = ws + OFF_POS;
    float* x1   = ws + OFF_X1;
    float* x2   = ws + OFF_X2;
    float* x3   = ws + OFF_X3;
    float* sf   = ws + OFF_SF;
    float* g    = ws + OFF_G;
    float* hi   = ws + OFF_HI;
    float* hj   = ws + OFF_HJ;
    float* hgb  = ws + OFF_HG;
    int*   flag = (int*)(ws + OFF_FLAG);
    int*   nidx = (int*)(ws + OFF_NIDX);
    float* d2   = ws + OFF_D2;
    float* gp   = ws + OFF_GP;

    // 1) detect input dtype (bf16 vs f32) on-device
    detect_kernel<<<1, 256, 0, stream>>>(d_in[0], flag);

    // 2) convert all inputs to f32 workspace
    InPtrs ip;
    for (int i = 0; i < 21; ++i) ip.p[i] = d_in[i];
    dim3 cgrid(672, 21);
    cvt_all_kernel<<<cgrid, 256, 0, stream>>>(ip, ws, flag);

    dim3 dgrid(16, 16);

    // 3) EdgeConv 1 (C=3 -> 32)
    for (int b = 0; b < NB; ++b) {
        dist_kernel<3><<<dgrid, 256, 0, stream>>>(posf, d2, b);
        select_kernel<<<NP / 4, 256, 0, stream>>>(d2, nidx, b);
    }
    edgeconv_kernel<3, 16, 32><<<NB * NP, 256, 0, stream>>>(
        posf, nidx, ws + OFF_C1W1, ws + OFF_C1B1, ws + OFF_C1W2, ws + OFF_C1B2, x1);

    // 4) EdgeConv 2 (C=32 -> 128)
    for (int b = 0; b < NB; ++b) {
        dist_kernel<32><<<dgrid, 256, 0, stream>>>(x1, d2, b);
        select_kernel<<<NP / 4, 256, 0, stream>>>(d2, nidx, b);
    }
    edgeconv_kernel<32, 64, 128><<<NB * NP, 256, 0, stream>>>(
        x1, nidx, ws + OFF_C2W1, ws + OFF_C2B1, ws + OFF_C2W2, ws + OFF_C2B2, x2);

    // 5) EdgeConv 3 (C=128 -> 512)
    for (int b = 0; b < NB; ++b) {
        dist_kernel<128><<<dgrid, 256, 0, stream>>>(x2, d2, b);
        select_kernel<<<NP / 4, 256, 0, stream>>>(d2, nidx, b);
    }
    edgeconv_kernel<128, 256, 512><<<NB * NP, 256, 0, stream>>>(
        x2, nidx, ws + OFF_C3W1, ws + OFF_C3B1, ws + OFF_C3W2, ws + OFF_C3B2, x3);

    // 6) shared MLP -> sf
    sm_kernel<<<NB * NP / 8, 256, 0, stream>>>(
        x1, x2, x3, ws + OFF_SMW1, ws + OFF_SMB1, ws + OFF_SMW2, ws + OFF_SMB2, sf);

    // 7) global max pool (two-stage)
    gmax1_kernel<<<NB * 25, 128, 0, stream>>>(sf, gp);
    gmax2_kernel<<<NB, 128, 0, stream>>>(gp, g);

    // 8) pair-feature projections
    hij_kernel<<<NB * NP / 8, 256, 0, stream>>>(sf, ws + OFF_ECW1, hi, hj);
    hg_kernel<<<NB, 128, 0, stream>>>(g, ws + OFF_ECW1, ws + OFF_ECB1, hgb);

    // 9) pairwise scorer
    dim3 pgrid(32, 32, NB);
    pair_kernel<<<pgrid, 256, 0, stream>>>(hi, hj, hgb, ws + OFF_ECW2, ws + OFF_ECB2,
                                           d_out, flag);
}

// Round 5
// 426.240 us; speedup vs baseline: 1.6888x; 1.2766x over previous
//
#include <hip/hip_runtime.h>
#include <hip/hip_bf16.h>
#include <cmath>

// Problem constants (B=2, N=1000, k=8 from reference)
#define NB 2
#define NP 1000
#define KNN 8
#define PPAIR 499500  // N*(N-1)/2

typedef __hip_bfloat16 bf16;
typedef unsigned long long u64;
typedef unsigned short ushort;
typedef unsigned int uint;
typedef __attribute__((ext_vector_type(8))) short short8;
typedef __attribute__((ext_vector_type(4))) float f32x4;

__device__ __forceinline__ float b2f(bf16 v) { return __bfloat162float(v); }
// f32 -> bf16 bits, round-to-nearest-even
__device__ __forceinline__ ushort f2b(float f) {
    uint x = __float_as_uint(f);
    return (ushort)((x + 0x7FFFu + ((x >> 16) & 1u)) >> 16);
}

// Workspace layout (float offsets), all 16B-aligned
#define OFF_POS    0
#define OFF_C1W1   6000
#define OFF_C1B1   6096
#define OFF_C1W2   6112
#define OFF_C1B2   6624
#define OFF_C2W1   6656
#define OFF_C2B1   10752
#define OFF_C2W2   10816
#define OFF_C2B2   19008
#define OFF_C3W1   19136
#define OFF_C3B1   84672
#define OFF_C3W2   84928
#define OFF_C3B2   216000
#define OFF_SMW1   216512
#define OFF_SMB1   388544
#define OFF_SMW2   388800
#define OFF_SMB2   421568
#define OFF_ECW1   421696
#define OFF_ECB1   470848
#define OFF_ECW2   470976
#define OFF_ECB2   471104
#define OFF_X1     471112
#define OFF_X2     535112
#define OFF_X3     791112
#define OFF_SF     1815112
#define OFF_G      2071112
#define OFF_HI     2071368
#define OFF_HJ     2327368
#define OFF_HG     2583368
#define OFF_FLAG   2583624   // int
#define OFF_NIDX   2583632   // 16000 ints
#define OFF_D2     2599632   // NB * 1000*1024 f32
#define OFF_GP     4647632   // 50*128 partial max
#define OFF_W1T    4654032   // 256x256 bf16 (32768 f32 slots)
#define OFF_W2T    4686800   // 512x256 bf16 (65536 f32 slots)

// ---------------- dtype detection ----------------
__global__ void detect_kernel(const void* pos, int* flag) {
    __shared__ float red[256];
    const unsigned short* p = (const unsigned short*)pos;
    float m = 0.f;
    for (int t = threadIdx.x; t < 6000; t += 256) {
        unsigned int u = ((unsigned int)p[t]) << 16;
        float v = fabsf(__uint_as_float(u));
        if (!isfinite(v)) v = 1e30f;
        m = fmaxf(m, v);
    }
    red[threadIdx.x] = m;
    __syncthreads();
    for (int s = 128; s > 0; s >>= 1) {
        if (threadIdx.x < s) red[threadIdx.x] = fmaxf(red[threadIdx.x], red[threadIdx.x + s]);
        __syncthreads();
    }
    if (threadIdx.x == 0) flag[0] = (red[0] > 1e6f) ? 1 : 0;
}

// ---------------- convert all 21 inputs to f32 workspace ----------------
struct InPtrs { const void* p[21]; };

__global__ void cvt_all_kernel(InPtrs in, float* ws, const int* flag) {
    const int sizes[21] = {6000, 96, 16, 512, 32, 4096, 64, 8192, 128,
                           65536, 256, 131072, 512, 172032, 256, 32768, 128,
                           49152, 128, 128, 1};
    const int offs[21] = {OFF_POS, OFF_C1W1, OFF_C1B1, OFF_C1W2, OFF_C1B2,
                          OFF_C2W1, OFF_C2B1, OFF_C2W2, OFF_C2B2,
                          OFF_C3W1, OFF_C3B1, OFF_C3W2, OFF_C3B2,
                          OFF_SMW1, OFF_SMB1, OFF_SMW2, OFF_SMB2,
                          OFF_ECW1, OFF_ECB1, OFF_ECW2, OFF_ECB2};
    int which = blockIdx.y;
    int n = sizes[which];
    int t = blockIdx.x * 256 + threadIdx.x;
    if (t >= n) return;
    float v;
    if (flag[0]) v = ((const float*)in.p[which])[t];
    else v = b2f(((const bf16*)in.p[which])[t]);
    ws[offs[which] + t] = v;
}

// ---------------- transpose+bf16 ec3 weights: W1T[h][c], W2T[o][h] ----------------
__global__ void wtrans_kernel(const float* __restrict__ ws, ushort* __restrict__ w1t,
                              ushort* __restrict__ w2t) {
    int t = blockIdx.x * 256 + threadIdx.x;
    if (blockIdx.y == 0) {
        if (t < 65536) {            // W1: [c=256][h=256] -> W1T[h][c]
            int h = t >> 8, c = t & 255;
            w1t[t] = f2b(ws[OFF_C3W1 + c * 256 + h]);
        }
    } else {
        if (t < 131072) {           // W2: [h=256][o=512] -> W2T[o][h]
            int o = t >> 8, h = t & 255;
            w2t[t] = f2b(ws[OFF_C3W2 + h * 512 + o]);
        }
    }
}

// ---------------- dist: tiled 64x64 squared-distance matrix (z = batch) ----------------
template <int C>
__global__ void dist_kernel(const float* __restrict__ x, float* __restrict__ d2g) {
    constexpr int CK = (C < 32) ? C : 32;
    constexpr int NCH = (C + CK - 1) / CK;
    __shared__ float As[64][CK + 1];
    __shared__ float Bs[64][CK + 1];
    int b = blockIdx.z;
    float* d2 = d2g + (size_t)b * 1024000;
    int tid = threadIdx.x;
    int i0 = blockIdx.y * 64, j0 = blockIdx.x * 64;
    int tx = tid & 15, ty = tid >> 4;
    float acc[4][4];
    #pragma unroll
    for (int r = 0; r < 4; ++r)
        #pragma unroll
        for (int s = 0; s < 4; ++s) acc[r][s] = 0.f;

    for (int ch = 0; ch < NCH; ++ch) {
        int k0 = ch * CK;
        for (int idx = tid; idx < 64 * CK; idx += 256) {
            int row = idx / CK, col = idx % CK;
            int gi = i0 + row, gj = j0 + row;
            As[row][col] = (gi < NP) ? x[((size_t)b * NP + gi) * C + k0 + col] : 0.f;
            Bs[row][col] = (gj < NP) ? x[((size_t)b * NP + gj) * C + k0 + col] : 0.f;
        }
        __syncthreads();
        #pragma unroll
        for (int k = 0; k < CK; ++k) {
            float av[4], bv[4];
            #pragma unroll
            for (int r = 0; r < 4; ++r) av[r] = As[ty * 4 + r][k];
            #pragma unroll
            for (int s = 0; s < 4; ++s) bv[s] = Bs[tx * 4 + s][k];
            #pragma unroll
            for (int r = 0; r < 4; ++r)
                #pragma unroll
                for (int s = 0; s < 4; ++s) {
                    float d = av[r] - bv[s];
                    acc[r][s] += d * d;
                }
        }
        __syncthreads();
    }
    #pragma unroll
    for (int r = 0; r < 4; ++r) {
        int i = i0 + ty * 4 + r;
        if (i < NP) {
            float4 v = make_float4(acc[r][0], acc[r][1], acc[r][2], acc[r][3]);
            *(float4*)(d2 + (size_t)i * 1024 + j0 + tx * 4) = v;
        }
    }
}

// ---------------- select: wave per query, coalesced row scan, top-8 ----------------
__device__ __forceinline__ void ce(u64& a, u64& b) {
    u64 lo = a < b ? a : b;
    u64 hi = a < b ? b : a;
    a = lo; b = hi;
}

__global__ void select_kernel(const float* __restrict__ d2g, int* __restrict__ nidx) {
    int lane = threadIdx.x & 63;
    int wave = threadIdx.x >> 6;
    int b = blockIdx.y;
    int i = blockIdx.x * 4 + wave;
    const float* row = d2g + (size_t)b * 1024000 + (size_t)i * 1024;

    u64 best[KNN];
    #pragma unroll
    for (int r = 0; r < KNN; ++r) best[r] = ~0ull;

    #pragma unroll
    for (int it = 0; it < 16; ++it) {
        int j = lane + it * 64;
        u64 cand = ~0ull;
        if (j < NP) cand = (((u64)__float_as_uint(row[j])) << 32) | (unsigned)j;
        u64 cur = cand;
        #pragma unroll
        for (int r = 0; r < KNN; ++r) {
            u64 lo = best[r] < cur ? best[r] : cur;
            u64 hi = best[r] < cur ? cur : best[r];
            best[r] = lo; cur = hi;
        }
    }

    #pragma unroll
    for (int m = 1; m < 64; m <<= 1) {
        u64 other[KNN];
        #pragma unroll
        for (int r = 0; r < KNN; ++r)
            other[r] = __shfl_xor((unsigned long long)best[r], m, 64);
        u64 v[KNN];
        #pragma unroll
        for (int r = 0; r < KNN; ++r)
            v[r] = best[r] < other[7 - r] ? best[r] : other[7 - r];
        ce(v[0], v[4]); ce(v[1], v[5]); ce(v[2], v[6]); ce(v[3], v[7]);
        ce(v[0], v[2]); ce(v[1], v[3]); ce(v[4], v[6]); ce(v[5], v[7]);
        ce(v[0], v[1]); ce(v[2], v[3]); ce(v[4], v[5]); ce(v[6], v[7]);
        #pragma unroll
        for (int r = 0; r < KNN; ++r) best[r] = v[r];
    }

    if (lane < KNN) nidx[((size_t)b * NP + i) * KNN + lane] = (int)(best[lane] & 0xffffffffu);
}

// ---------------- fused EdgeConv (f32, small layers 1 & 2) ----------------
template <int CIN, int CHID, int COUT>
__global__ void edgeconv_kernel(const float* __restrict__ x, const int* __restrict__ nidx,
                                const float* __restrict__ w1, const float* __restrict__ b1,
                                const float* __restrict__ w2, const float* __restrict__ b2,
                                float* __restrict__ y) {
    int bi = blockIdx.x;
    int b = bi / NP;
    __shared__ float xi[CIN];
    __shared__ float dx[KNN][CIN];
    __shared__ __align__(16) float hid[CHID][12];
    __shared__ int nb[KNN];
    int tid = threadIdx.x;
    if (tid < KNN) nb[tid] = nidx[bi * KNN + tid];
    for (int c = tid; c < CIN; c += 256) xi[c] = x[(size_t)bi * CIN + c];
    __syncthreads();
    for (int t = tid; t < KNN * CIN; t += 256) {
        int k = t / CIN, c = t % CIN;
        dx[k][c] = x[((size_t)b * NP + nb[k]) * CIN + c] - xi[c];
    }
    __syncthreads();
    for (int h = tid; h < CHID; h += 256) {
        float common = b1[h];
        for (int c = 0; c < CIN; ++c) common += xi[c] * w1[c * CHID + h];
        float acc[KNN];
        for (int k = 0; k < KNN; ++k) acc[k] = common;
        for (int c = 0; c < CIN; ++c) {
            float wv = w1[(CIN + c) * CHID + h];
            for (int k = 0; k < KNN; ++k) acc[k] += dx[k][c] * wv;
        }
        for (int k = 0; k < KNN; ++k) hid[h][k] = fmaxf(acc[k], 0.f);
    }
    __syncthreads();
    for (int o = tid; o < COUT; o += 256) {
        float acc[KNN];
        for (int k = 0; k < KNN; ++k) acc[k] = 0.f;
        for (int h = 0; h < CHID; ++h) {
            float wv = w2[h * COUT + o];
            float4 h0 = *(const float4*)&hid[h][0];
            float4 h1 = *(const float4*)&hid[h][4];
            acc[0] += h0.x * wv; acc[1] += h0.y * wv; acc[2] += h0.z * wv; acc[3] += h0.w * wv;
            acc[4] += h1.x * wv; acc[5] += h1.y * wv; acc[6] += h1.z * wv; acc[7] += h1.w * wv;
        }
        float m = acc[0];
        for (int k = 1; k < KNN; ++k) m = fmaxf(m, acc[k]);
        y[(size_t)bi * COUT + o] = m + b2[o];
    }
}

// ---------------- EdgeConv-3 via bf16 MFMA, fully fused ----------------
// Block = 4 points (32 edge rows). E[32][256] bf16 in LDS -> GEMM1(relu) ->
// H[32][256] bf16 in LDS -> GEMM2 + max-over-8 epilogue -> x3[4][512] f32.
// MFMA 16x16x32_bf16: A[m=lane&15][k=quad*8+j]; C/D col=lane&15,row=quad*4+reg.
#define ESTR 264   // LDS row stride (bf16 elems): 264*2=528B = 4-bank shift/row
__global__ __launch_bounds__(256) void ec3_mfma_kernel(
        const float* __restrict__ x2, const int* __restrict__ nidx,
        const ushort* __restrict__ w1t, const ushort* __restrict__ w2t,
        const float* __restrict__ b1f, const float* __restrict__ b2f,
        float* __restrict__ x3) {
    __shared__ ushort Elds[32 * ESTR];
    __shared__ ushort Hlds[32 * ESTR];
    int tid = threadIdx.x;
    int P0 = blockIdx.x * 4;            // first global point of this block

    // ---- stage edge features: e = local edge (0..31), 8 col-chunks of 16
    {
        int e = tid >> 3, seg = tid & 7;
        int bi = P0 + (e >> 3), k = e & 7;
        int b = bi / NP;
        int nb = nidx[bi * KNN + k];
        const float* xi = x2 + (size_t)bi * 128;
        const float* xj = x2 + ((size_t)b * NP + nb) * 128;
        int c0 = seg * 16;
        #pragma unroll
        for (int c = c0; c < c0 + 16; c += 4) {
            float4 a = *(const float4*)(xi + c);
            float4 q = *(const float4*)(xj + c);
            uint lo = (uint)f2b(a.x) | ((uint)f2b(a.y) << 16);
            uint hi = (uint)f2b(a.z) | ((uint)f2b(a.w) << 16);
            *(uint2*)(&Elds[e * ESTR + c]) = make_uint2(lo, hi);
            lo = (uint)f2b(q.x - a.x) | ((uint)f2b(q.y - a.y) << 16);
            hi = (uint)f2b(q.z - a.z) | ((uint)f2b(q.w - a.w) << 16);
            *(uint2*)(&Elds[e * ESTR + 128 + c]) = make_uint2(lo, hi);
        }
    }
    __syncthreads();

    int lane = tid & 63, wave = tid >> 6;
    int n16 = lane & 15, quad = lane >> 4;

    // ---- GEMM1: H = relu(E @ W1 + b1); wave covers 64 cols
    {
        int nc = wave * 64;
        f32x4 acc1[2][4];
        #pragma unroll
        for (int mt = 0; mt < 2; ++mt)
            #pragma unroll
            for (int nt = 0; nt < 4; ++nt) {
                float bv = b1f[nc + nt * 16 + n16];
                acc1[mt][nt] = (f32x4){bv, bv, bv, bv};
            }
        #pragma unroll
        for (int k8 = 0; k8 < 8; ++k8) {
            int ko = k8 * 32 + quad * 8;
            short8 a0 = *(const short8*)(&Elds[(n16) * ESTR + ko]);
            short8 a1 = *(const short8*)(&Elds[(16 + n16) * ESTR + ko]);
            #pragma unroll
            for (int nt = 0; nt < 4; ++nt) {
                short8 bfr = *(const short8*)(&w1t[(size_t)(nc + nt * 16 + n16) * 256 + ko]);
                acc1[0][nt] = __builtin_amdgcn_mfma_f32_16x16x32_bf16(a0, bfr, acc1[0][nt], 0, 0, 0);
                acc1[1][nt] = __builtin_amdgcn_mfma_f32_16x16x32_bf16(a1, bfr, acc1[1][nt], 0, 0, 0);
            }
        }
        #pragma unroll
        for (int mt = 0; mt < 2; ++mt)
            #pragma unroll
            for (int nt = 0; nt < 4; ++nt) {
                int col = nc + nt * 16 + n16;
                #pragma unroll
                for (int r = 0; r < 4; ++r) {
                    int row = mt * 16 + quad * 4 + r;
                    Hlds[row * ESTR + col] = f2b(fmaxf(acc1[mt][nt][r], 0.f));
                }
            }
    }
    __syncthreads();

    // ---- GEMM2: O = H @ W2 (+b2 at write); wave covers 128 cols; max over k=8
    {
        int nc2 = wave * 128;
        f32x4 acc2[2][8];
        #pragma unroll
        for (int mt = 0; mt < 2; ++mt)
            #pragma unroll
            for (int nt = 0; nt < 8; ++nt) acc2[mt][nt] = (f32x4){0.f, 0.f, 0.f, 0.f};
        #pragma unroll
        for (int k8 = 0; k8 < 8; ++k8) {
            int ko = k8 * 32 + quad * 8;
            short8 a0 = *(const short8*)(&Hlds[(n16) * ESTR + ko]);
            short8 a1 = *(const short8*)(&Hlds[(16 + n16) * ESTR + ko]);
            #pragma unroll
            for (int nt = 0; nt < 8; ++nt) {
                short8 bfr = *(const short8*)(&w2t[(size_t)(nc2 + nt * 16 + n16) * 256 + ko]);
                acc2[0][nt] = __builtin_amdgcn_mfma_f32_16x16x32_bf16(a0, bfr, acc2[0][nt], 0, 0, 0);
                acc2[1][nt] = __builtin_amdgcn_mfma_f32_16x16x32_bf16(a1, bfr, acc2[1][nt], 0, 0, 0);
            }
        }
        // epilogue: per 16-row tile, rows 0-7 = point 2mt, rows 8-15 = point 2mt+1
        #pragma unroll
        for (int mt = 0; mt < 2; ++mt)
            #pragma unroll
            for (int nt = 0; nt < 8; ++nt) {
                f32x4 a = acc2[mt][nt];
                float v = fmaxf(fmaxf(a[0], a[1]), fmaxf(a[2], a[3]));
                float o = fmaxf(v, __shfl_xor(v, 16, 64));
                int col = nc2 + nt * 16 + n16;
                if (quad == 0)
                    x3[(size_t)(P0 + mt * 2) * 512 + col] = o + b2f[col];
                else if (quad == 2)
                    x3[(size_t)(P0 + mt * 2 + 1) * 512 + col] = o + b2f[col];
            }
    }
}

// ---------------- shared MLP on concat[x1,x2,x3]: 672->256 relu ->128 ----------------
__global__ void sm_kernel(const float* __restrict__ x1, const float* __restrict__ x2,
                          const float* __restrict__ x3,
                          const float* __restrict__ w1, const float* __restrict__ b1,
                          const float* __restrict__ w2, const float* __restrict__ b2,
                          float* __restrict__ sf) {
    int p0 = blockIdx.x * 8;
    __shared__ float in[8][672];
    __shared__ __align__(16) float hid[256][12];
    int tid = threadIdx.x;
    for (int t = tid; t < 8 * 672; t += 256) {
        int k = t / 672, c = t % 672;
        int p = p0 + k;
        float v;
        if (c < 32) v = x1[(size_t)p * 32 + c];
        else if (c < 160) v = x2[(size_t)p * 128 + (c - 32)];
        else v = x3[(size_t)p * 512 + (c - 160)];
        in[k][c] = v;
    }
    __syncthreads();
    {
        int h = tid;
        float acc[8];
        float bb = b1[h];
        for (int k = 0; k < 8; ++k) acc[k] = bb;
        for (int c = 0; c < 672; ++c) {
            float wv = w1[c * 256 + h];
            for (int k = 0; k < 8; ++k) acc[k] += in[k][c] * wv;
        }
        for (int k = 0; k < 8; ++k) hid[h][k] = fmaxf(acc[k], 0.f);
    }
    __syncthreads();
    if (tid < 128) {
        int o = tid;
        float acc[8];
        float bb = b2[o];
        for (int k = 0; k < 8; ++k) acc[k] = bb;
        for (int h = 0; h < 256; ++h) {
            float wv = w2[h * 128 + o];
            float4 h0 = *(const float4*)&hid[h][0];
            float4 h1 = *(const float4*)&hid[h][4];
            acc[0] += h0.x * wv; acc[1] += h0.y * wv; acc[2] += h0.z * wv; acc[3] += h0.w * wv;
            acc[4] += h1.x * wv; acc[5] += h1.y * wv; acc[6] += h1.z * wv; acc[7] += h1.w * wv;
        }
        for (int k = 0; k < 8; ++k) sf[((size_t)p0 + k) * 128 + o] = acc[k];
    }
}

// ---------------- global max pool, two-stage ----------------
__global__ void gmax1_kernel(const float* __restrict__ sf, float* __restrict__ part) {
    int m = blockIdx.x;
    int b = m / 25, ch = m % 25, o = threadIdx.x;
    float v = -INFINITY;
    int n0 = ch * 40;
    for (int n = n0; n < n0 + 40; ++n)
        v = fmaxf(v, sf[((size_t)b * NP + n) * 128 + o]);
    part[(size_t)m * 128 + o] = v;
}

__global__ void gmax2_kernel(const float* __restrict__ part, float* __restrict__ g) {
    int b = blockIdx.x, o = threadIdx.x;
    float v = -INFINITY;
    for (int ch = 0; ch < 25; ++ch)
        v = fmaxf(v, part[((size_t)b * 25 + ch) * 128 + o]);
    g[b * 128 + o] = v;
}

// ---------------- hi = sf @ W[:128], hj = sf @ W[128:256] ----------------
__global__ void hij_kernel(const float* __restrict__ sf, const float* __restrict__ w1,
                           float* __restrict__ hi, float* __restrict__ hj) {
    int p0 = blockIdx.x * 8;
    __shared__ float in[8][128];
    int tid = threadIdx.x;
    for (int t = tid; t < 8 * 128; t += 256) in[t >> 7][t & 127] = sf[(size_t)p0 * 128 + t];
    __syncthreads();
    int sel = tid >> 7, o = tid & 127;
    float acc[8];
    for (int k = 0; k < 8; ++k) acc[k] = 0.f;
    for (int c = 0; c < 128; ++c) {
        float wv = w1[(sel * 128 + c) * 128 + o];
        for (int k = 0; k < 8; ++k) acc[k] += in[k][c] * wv;
    }
    float* dst = sel ? hj : hi;
    for (int k = 0; k < 8; ++k) dst[((size_t)p0 + k) * 128 + o] = acc[k];
}

// ---------------- hg = g @ W[256:384] + b1 ----------------
__global__ void hg_kernel(const float* __restrict__ g, const float* __restrict__ w1,
                          const float* __restrict__ b1, float* __restrict__ hg) {
    int b = blockIdx.x, o = threadIdx.x;
    float acc = b1[o];
    for (int c = 0; c < 128; ++c) acc += g[b * 128 + c] * w1[(256 + c) * 128 + o];
    hg[b * 128 + o] = acc;
}

// ---------------- pairwise scorer over 32x32 tiles of (i,j), i<j ----------------
__global__ void pair_kernel(const float* __restrict__ hi, const float* __restrict__ hj,
                            const float* __restrict__ hg,
                            const float* __restrict__ w2, const float* __restrict__ b2,
                            void* __restrict__ out, const int* __restrict__ flag) {
    int j0 = blockIdx.x * 32, i0 = blockIdx.y * 32, b = blockIdx.z;
    if (j0 + 31 <= i0) return;
    __shared__ float hit[32][129];
    __shared__ float hjt[32][129];
    __shared__ float hgs[128];
    __shared__ float w2s[128];
    int tid = threadIdx.x;
    if (tid < 128) {
        hgs[tid] = hg[b * 128 + tid];
        w2s[tid] = w2[tid];
    }
    for (int t = tid; t < 32 * 128; t += 256) {
        int r = t >> 7, c = t & 127;
        int i = i0 + r, j = j0 + r;
        hit[r][c] = (i < NP) ? hi[((size_t)b * NP + i) * 128 + c] : 0.f;
        hjt[r][c] = (j < NP) ? hj[((size_t)b * NP + j) * 128 + c] : 0.f;
    }
    __syncthreads();
    float bb = b2[0];
    int f = flag[0];
    int tj = tid & 31;
    int ti0 = tid >> 5;
    int j = j0 + tj;
    float acc[4] = {0.f, 0.f, 0.f, 0.f};
    for (int o = 0; o < 128; ++o) {
        float hv = hjt[tj][o] + hgs[o];
        float wv = w2s[o];
        acc[0] += fmaxf(hit[ti0][o] + hv, 0.f) * wv;
        acc[1] += fmaxf(hit[ti0 + 8][o] + hv, 0.f) * wv;
        acc[2] += fmaxf(hit[ti0 + 16][o] + hv, 0.f) * wv;
        acc[3] += fmaxf(hit[ti0 + 24][o] + hv, 0.f) * wv;
    }
    for (int r = 0; r < 4; ++r) {
        int i = i0 + ti0 + 8 * r;
        if (i < j && j < NP) {
            size_t p = (size_t)i * (NP - 1) - (size_t)i * (i - 1) / 2 + (j - i - 1);
            float mo = acc[r] + bb;
            float pr = 1.f / (1.f + expf(-mo));
            size_t idx0 = (size_t)b * PPAIR + p;
            size_t idx1 = (size_t)NB * PPAIR + idx0;
            if (f) {
                ((float*)out)[idx0] = pr;
                ((float*)out)[idx1] = mo;
            } else {
                ((bf16*)out)[idx0] = __float2bfloat16(pr);
                ((bf16*)out)[idx1] = __float2bfloat16(mo);
            }
        }
    }
}

extern "C" void kernel_launch(void* const* d_in, const int* in_sizes, int n_in,
                              void* d_out, int out_size, void* d_ws, size_t ws_size,
                              hipStream_t stream) {
    float* ws = (float*)d_ws;
    float* posf = ws + OFF_POS;
    float* x1   = ws + OFF_X1;
    float* x2   = ws + OFF_X2;
    float* x3   = ws + OFF_X3;
    float* sf   = ws + OFF_SF;
    float* g    = ws + OFF_G;
    float* hi   = ws + OFF_HI;
    float* hj   = ws + OFF_HJ;
    float* hgb  = ws + OFF_HG;
    int*   flag = (int*)(ws + OFF_FLAG);
    int*   nidx = (int*)(ws + OFF_NIDX);
    float* d2   = ws + OFF_D2;
    float* gp   = ws + OFF_GP;
    ushort* w1t = (ushort*)(ws + OFF_W1T);
    ushort* w2t = (ushort*)(ws + OFF_W2T);

    // 1) detect input dtype (bf16 vs f32) on-device
    detect_kernel<<<1, 256, 0, stream>>>(d_in[0], flag);

    // 2) convert all inputs to f32 workspace; transpose/bf16 ec3 weights
    InPtrs ip;
    for (int i = 0; i < 21; ++i) ip.p[i] = d_in[i];
    dim3 cgrid(672, 21);
    cvt_all_kernel<<<cgrid, 256, 0, stream>>>(ip, ws, flag);
    dim3 wgrid(512, 2);
    wtrans_kernel<<<wgrid, 256, 0, stream>>>(ws, w1t, w2t);

    dim3 dgrid(16, 16, NB);
    dim3 sgrid(NP / 4, NB);

    // 3) EdgeConv 1 (C=3 -> 32)
    dist_kernel<3><<<dgrid, 256, 0, stream>>>(posf, d2);
    select_kernel<<<sgrid, 256, 0, stream>>>(d2, nidx);
    edgeconv_kernel<3, 16, 32><<<NB * NP, 256, 0, stream>>>(
        posf, nidx, ws + OFF_C1W1, ws + OFF_C1B1, ws + OFF_C1W2, ws + OFF_C1B2, x1);

    // 4) EdgeConv 2 (C=32 -> 128)
    dist_kernel<32><<<dgrid, 256, 0, stream>>>(x1, d2);
    select_kernel<<<sgrid, 256, 0, stream>>>(d2, nidx);
    edgeconv_kernel<32, 64, 128><<<NB * NP, 256, 0, stream>>>(
        x1, nidx, ws + OFF_C2W1, ws + OFF_C2B1, ws + OFF_C2W2, ws + OFF_C2B2, x2);

    // 5) EdgeConv 3 (C=128 -> 512) via MFMA
    dist_kernel<128><<<dgrid, 256, 0, stream>>>(x2, d2);
    select_kernel<<<sgrid, 256, 0, stream>>>(d2, nidx);
    ec3_mfma_kernel<<<NB * NP / 4, 256, 0, stream>>>(
        x2, nidx, w1t, w2t, ws + OFF_C3B1, ws + OFF_C3B2, x3);

    // 6) shared MLP -> sf
    sm_kernel<<<NB * NP / 8, 256, 0, stream>>>(
        x1, x2, x3, ws + OFF_SMW1, ws + OFF_SMB1, ws + OFF_SMW2, ws + OFF_SMB2, sf);

    // 7) global max pool (two-stage)
    gmax1_kernel<<<NB * 25, 128, 0, stream>>>(sf, gp);
    gmax2_kernel<<<NB, 128, 0, stream>>>(gp, g);

    // 8) pair-feature projections
    hij_kernel<<<NB * NP / 8, 256, 0, stream>>>(sf, ws + OFF_ECW1, hi, hj);
    hg_kernel<<<NB, 128, 0, stream>>>(g, ws + OFF_ECW1, ws + OFF_ECB1, hgb);

    // 9) pairwise scorer
    dim3 pgrid(32, 32, NB);
    pair_kernel<<<pgrid, 256, 0, stream>>>(hi, hj, hgb, ws + OFF_ECW2, ws + OFF_ECB2,
                                           d_out, flag);
}

// Round 6
// 356.100 us; speedup vs baseline: 2.0214x; 1.1970x over previous
//
#include <hip/hip_runtime.h>
#include <hip/hip_bf16.h>
#include <cmath>

// Problem constants (B=2, N=1000, k=8 from reference)
#define NB 2
#define NP 1000
#define KNN 8
#define PPAIR 499500  // N*(N-1)/2

typedef __hip_bfloat16 bf16;
typedef unsigned long long u64;
typedef unsigned short ushort;
typedef unsigned int uint;
typedef __attribute__((ext_vector_type(8))) short short8;
typedef __attribute__((ext_vector_type(4))) float f32x4;

__device__ __forceinline__ float b2f(bf16 v) { return __bfloat162float(v); }
// f32 -> bf16 bits, round-to-nearest-even
__device__ __forceinline__ ushort f2b(float f) {
    uint x = __float_as_uint(f);
    return (ushort)((x + 0x7FFFu + ((x >> 16) & 1u)) >> 16);
}

// Workspace layout (float offsets), all 16B-aligned
#define OFF_POS    0
#define OFF_C1W1   6000
#define OFF_C1B1   6096
#define OFF_C1W2   6112
#define OFF_C1B2   6624
#define OFF_C2W1   6656
#define OFF_C2B1   10752
#define OFF_C2W2   10816
#define OFF_C2B2   19008
#define OFF_C3W1   19136
#define OFF_C3B1   84672
#define OFF_C3W2   84928
#define OFF_C3B2   216000
#define OFF_SMW1   216512
#define OFF_SMB1   388544
#define OFF_SMW2   388800
#define OFF_SMB2   421568
#define OFF_ECW1   421696
#define OFF_ECB1   470848
#define OFF_ECW2   470976
#define OFF_ECB2   471104
#define OFF_X1     471112
#define OFF_X2     535112
#define OFF_X3     791112
#define OFF_SF     1815112
#define OFF_G      2071112
#define OFF_HI     2071368
#define OFF_HJ     2327368
#define OFF_HG     2583368
#define OFF_FLAG   2583624   // int
#define OFF_NIDX   2583632   // 16000 ints
#define OFF_D2     2599632   // NB * 1000*1024 f32
#define OFF_GP     4647632   // 50*128 partial max
#define OFF_W1T    4654032   // ec3 W1T 256x256 bf16 (32768 f32)
#define OFF_W2T    4686800   // ec3 W2T 512x256 bf16 (65536 f32)
#define OFF_SMW1T  4752336   // sm W1T 256x672 bf16 (86016 f32)
#define OFF_SMW2T  4838352   // sm W2T 128x256 bf16 (16384 f32)
#define OFF_ECW1T  4854736   // hij WT 256x128 bf16 (16384 f32)

// ---------------- dtype detection ----------------
__global__ void detect_kernel(const void* pos, int* flag) {
    __shared__ float red[256];
    const unsigned short* p = (const unsigned short*)pos;
    float m = 0.f;
    for (int t = threadIdx.x; t < 6000; t += 256) {
        unsigned int u = ((unsigned int)p[t]) << 16;
        float v = fabsf(__uint_as_float(u));
        if (!isfinite(v)) v = 1e30f;
        m = fmaxf(m, v);
    }
    red[threadIdx.x] = m;
    __syncthreads();
    for (int s = 128; s > 0; s >>= 1) {
        if (threadIdx.x < s) red[threadIdx.x] = fmaxf(red[threadIdx.x], red[threadIdx.x + s]);
        __syncthreads();
    }
    if (threadIdx.x == 0) flag[0] = (red[0] > 1e6f) ? 1 : 0;
}

// ---------------- convert all 21 inputs to f32 workspace ----------------
struct InPtrs { const void* p[21]; };

__global__ void cvt_all_kernel(InPtrs in, float* ws, const int* flag) {
    const int sizes[21] = {6000, 96, 16, 512, 32, 4096, 64, 8192, 128,
                           65536, 256, 131072, 512, 172032, 256, 32768, 128,
                           49152, 128, 128, 1};
    const int offs[21] = {OFF_POS, OFF_C1W1, OFF_C1B1, OFF_C1W2, OFF_C1B2,
                          OFF_C2W1, OFF_C2B1, OFF_C2W2, OFF_C2B2,
                          OFF_C3W1, OFF_C3B1, OFF_C3W2, OFF_C3B2,
                          OFF_SMW1, OFF_SMB1, OFF_SMW2, OFF_SMB2,
                          OFF_ECW1, OFF_ECB1, OFF_ECW2, OFF_ECB2};
    int which = blockIdx.y;
    int n = sizes[which];
    int t = blockIdx.x * 256 + threadIdx.x;
    if (t >= n) return;
    float v;
    if (flag[0]) v = ((const float*)in.p[which])[t];
    else v = b2f(((const bf16*)in.p[which])[t]);
    ws[offs[which] + t] = v;
}

// ---------------- transpose+bf16 weights for all MFMA kernels ----------------
__global__ void wtrans_kernel(const float* __restrict__ ws, ushort* __restrict__ w1t,
                              ushort* __restrict__ w2t, ushort* __restrict__ smw1t,
                              ushort* __restrict__ smw2t, ushort* __restrict__ ecw1t) {
    int t = blockIdx.x * 256 + threadIdx.x;
    int y = blockIdx.y;
    if (y == 0) {
        if (t < 65536) {            // ec3 W1 [c=256][h=256] -> [h][c]
            int h = t >> 8, c = t & 255;
            w1t[t] = f2b(ws[OFF_C3W1 + c * 256 + h]);
        }
    } else if (y == 1) {
        if (t < 131072) {           // ec3 W2 [h=256][o=512] -> [o][h]
            int o = t >> 8, h = t & 255;
            w2t[t] = f2b(ws[OFF_C3W2 + h * 512 + o]);
        }
    } else if (y == 2) {
        if (t < 172032) {           // sm W1 [c=672][h=256] -> [h][c]
            int h = t / 672, c = t - h * 672;
            smw1t[t] = f2b(ws[OFF_SMW1 + c * 256 + h]);
        }
    } else if (y == 3) {
        if (t < 32768) {            // sm W2 [h=256][o=128] -> [o][h]
            int o = t >> 8, h = t & 255;
            smw2t[t] = f2b(ws[OFF_SMW2 + h * 128 + o]);
        }
    } else {
        if (t < 32768) {            // ec W1[:256] [c(+128 for hj)][o=128] -> [o'][c]
            int op = t >> 7, c = t & 127;
            float v = (op < 128) ? ws[OFF_ECW1 + c * 128 + op]
                                 : ws[OFF_ECW1 + (128 + c) * 128 + (op - 128)];
            ecw1t[t] = f2b(v);
        }
    }
}

// ---------------- dist: tiled 64x64 squared-distance matrix (z = batch) ----------------
template <int C>
__global__ void dist_kernel(const float* __restrict__ x, float* __restrict__ d2g) {
    constexpr int CK = (C < 32) ? C : 32;
    constexpr int NCH = (C + CK - 1) / CK;
    __shared__ float As[64][CK + 1];
    __shared__ float Bs[64][CK + 1];
    int b = blockIdx.z;
    float* d2 = d2g + (size_t)b * 1024000;
    int tid = threadIdx.x;
    int i0 = blockIdx.y * 64, j0 = blockIdx.x * 64;
    int tx = tid & 15, ty = tid >> 4;
    float acc[4][4];
    #pragma unroll
    for (int r = 0; r < 4; ++r)
        #pragma unroll
        for (int s = 0; s < 4; ++s) acc[r][s] = 0.f;

    for (int ch = 0; ch < NCH; ++ch) {
        int k0 = ch * CK;
        for (int idx = tid; idx < 64 * CK; idx += 256) {
            int row = idx / CK, col = idx % CK;
            int gi = i0 + row, gj = j0 + row;
            As[row][col] = (gi < NP) ? x[((size_t)b * NP + gi) * C + k0 + col] : 0.f;
            Bs[row][col] = (gj < NP) ? x[((size_t)b * NP + gj) * C + k0 + col] : 0.f;
        }
        __syncthreads();
        #pragma unroll
        for (int k = 0; k < CK; ++k) {
            float av[4], bv[4];
            #pragma unroll
            for (int r = 0; r < 4; ++r) av[r] = As[ty * 4 + r][k];
            #pragma unroll
            for (int s = 0; s < 4; ++s) bv[s] = Bs[tx * 4 + s][k];
            #pragma unroll
            for (int r = 0; r < 4; ++r)
                #pragma unroll
                for (int s = 0; s < 4; ++s) {
                    float d = av[r] - bv[s];
                    acc[r][s] += d * d;
                }
        }
        __syncthreads();
    }
    #pragma unroll
    for (int r = 0; r < 4; ++r) {
        int i = i0 + ty * 4 + r;
        if (i < NP) {
            float4 v = make_float4(acc[r][0], acc[r][1], acc[r][2], acc[r][3]);
            *(float4*)(d2 + (size_t)i * 1024 + j0 + tx * 4) = v;
        }
    }
}

// ---------------- select: wave per query, coalesced row scan, top-8 ----------------
__device__ __forceinline__ void ce(u64& a, u64& b) {
    u64 lo = a < b ? a : b;
    u64 hi = a < b ? b : a;
    a = lo; b = hi;
}

__global__ void select_kernel(const float* __restrict__ d2g, int* __restrict__ nidx) {
    int lane = threadIdx.x & 63;
    int wave = threadIdx.x >> 6;
    int b = blockIdx.y;
    int i = blockIdx.x * 4 + wave;
    const float* row = d2g + (size_t)b * 1024000 + (size_t)i * 1024;

    u64 best[KNN];
    #pragma unroll
    for (int r = 0; r < KNN; ++r) best[r] = ~0ull;

    #pragma unroll
    for (int it = 0; it < 16; ++it) {
        int j = lane + it * 64;
        u64 cand = ~0ull;
        if (j < NP) cand = (((u64)__float_as_uint(row[j])) << 32) | (unsigned)j;
        u64 cur = cand;
        #pragma unroll
        for (int r = 0; r < KNN; ++r) {
            u64 lo = best[r] < cur ? best[r] : cur;
            u64 hi = best[r] < cur ? cur : best[r];
            best[r] = lo; cur = hi;
        }
    }

    #pragma unroll
    for (int m = 1; m < 64; m <<= 1) {
        u64 other[KNN];
        #pragma unroll
        for (int r = 0; r < KNN; ++r)
            other[r] = __shfl_xor((unsigned long long)best[r], m, 64);
        u64 v[KNN];
        #pragma unroll
        for (int r = 0; r < KNN; ++r)
            v[r] = best[r] < other[7 - r] ? best[r] : other[7 - r];
        ce(v[0], v[4]); ce(v[1], v[5]); ce(v[2], v[6]); ce(v[3], v[7]);
        ce(v[0], v[2]); ce(v[1], v[3]); ce(v[4], v[6]); ce(v[5], v[7]);
        ce(v[0], v[1]); ce(v[2], v[3]); ce(v[4], v[5]); ce(v[6], v[7]);
        #pragma unroll
        for (int r = 0; r < KNN; ++r) best[r] = v[r];
    }

    if (lane < KNN) nidx[((size_t)b * NP + i) * KNN + lane] = (int)(best[lane] & 0xffffffffu);
}

// ---------------- fused EdgeConv (f32, small layers 1 & 2) ----------------
template <int CIN, int CHID, int COUT>
__global__ void edgeconv_kernel(const float* __restrict__ x, const int* __restrict__ nidx,
                                const float* __restrict__ w1, const float* __restrict__ b1,
                                const float* __restrict__ w2, const float* __restrict__ b2,
                                float* __restrict__ y) {
    int bi = blockIdx.x;
    int b = bi / NP;
    __shared__ float xi[CIN];
    __shared__ float dx[KNN][CIN];
    __shared__ __align__(16) float hid[CHID][12];
    __shared__ int nb[KNN];
    int tid = threadIdx.x;
    if (tid < KNN) nb[tid] = nidx[bi * KNN + tid];
    for (int c = tid; c < CIN; c += 256) xi[c] = x[(size_t)bi * CIN + c];
    __syncthreads();
    for (int t = tid; t < KNN * CIN; t += 256) {
        int k = t / CIN, c = t % CIN;
        dx[k][c] = x[((size_t)b * NP + nb[k]) * CIN + c] - xi[c];
    }
    __syncthreads();
    for (int h = tid; h < CHID; h += 256) {
        float common = b1[h];
        for (int c = 0; c < CIN; ++c) common += xi[c] * w1[c * CHID + h];
        float acc[KNN];
        for (int k = 0; k < KNN; ++k) acc[k] = common;
        for (int c = 0; c < CIN; ++c) {
            float wv = w1[(CIN + c) * CHID + h];
            for (int k = 0; k < KNN; ++k) acc[k] += dx[k][c] * wv;
        }
        for (int k = 0; k < KNN; ++k) hid[h][k] = fmaxf(acc[k], 0.f);
    }
    __syncthreads();
    for (int o = tid; o < COUT; o += 256) {
        float acc[KNN];
        for (int k = 0; k < KNN; ++k) acc[k] = 0.f;
        for (int h = 0; h < CHID; ++h) {
            float wv = w2[h * COUT + o];
            float4 h0 = *(const float4*)&hid[h][0];
            float4 h1 = *(const float4*)&hid[h][4];
            acc[0] += h0.x * wv; acc[1] += h0.y * wv; acc[2] += h0.z * wv; acc[3] += h0.w * wv;
            acc[4] += h1.x * wv; acc[5] += h1.y * wv; acc[6] += h1.z * wv; acc[7] += h1.w * wv;
        }
        float m = acc[0];
        for (int k = 1; k < KNN; ++k) m = fmaxf(m, acc[k]);
        y[(size_t)bi * COUT + o] = m + b2[o];
    }
}

// ---------------- EdgeConv-3 via bf16 MFMA, fully fused ----------------
// MFMA 16x16x32_bf16: A[m=lane&15][k=quad*8+j]; C/D col=lane&15,row=quad*4+reg.
#define ESTR 264   // LDS row stride (bf16 elems)
__global__ __launch_bounds__(256) void ec3_mfma_kernel(
        const float* __restrict__ x2, const int* __restrict__ nidx,
        const ushort* __restrict__ w1t, const ushort* __restrict__ w2t,
        const float* __restrict__ b1f, const float* __restrict__ b2f,
        float* __restrict__ x3) {
    __shared__ ushort Elds[32 * ESTR];
    __shared__ ushort Hlds[32 * ESTR];
    int tid = threadIdx.x;
    int P0 = blockIdx.x * 4;

    {
        int e = tid >> 3, seg = tid & 7;
        int bi = P0 + (e >> 3), k = e & 7;
        int b = bi / NP;
        int nb = nidx[bi * KNN + k];
        const float* xi = x2 + (size_t)bi * 128;
        const float* xj = x2 + ((size_t)b * NP + nb) * 128;
        int c0 = seg * 16;
        #pragma unroll
        for (int c = c0; c < c0 + 16; c += 4) {
            float4 a = *(const float4*)(xi + c);
            float4 q = *(const float4*)(xj + c);
            uint lo = (uint)f2b(a.x) | ((uint)f2b(a.y) << 16);
            uint hi = (uint)f2b(a.z) | ((uint)f2b(a.w) << 16);
            *(uint2*)(&Elds[e * ESTR + c]) = make_uint2(lo, hi);
            lo = (uint)f2b(q.x - a.x) | ((uint)f2b(q.y - a.y) << 16);
            hi = (uint)f2b(q.z - a.z) | ((uint)f2b(q.w - a.w) << 16);
            *(uint2*)(&Elds[e * ESTR + 128 + c]) = make_uint2(lo, hi);
        }
    }
    __syncthreads();

    int lane = tid & 63, wave = tid >> 6;
    int n16 = lane & 15, quad = lane >> 4;

    {
        int nc = wave * 64;
        f32x4 acc1[2][4];
        #pragma unroll
        for (int mt = 0; mt < 2; ++mt)
            #pragma unroll
            for (int nt = 0; nt < 4; ++nt) {
                float bv = b1f[nc + nt * 16 + n16];
                acc1[mt][nt] = (f32x4){bv, bv, bv, bv};
            }
        #pragma unroll
        for (int k8 = 0; k8 < 8; ++k8) {
            int ko = k8 * 32 + quad * 8;
            short8 a0 = *(const short8*)(&Elds[(n16) * ESTR + ko]);
            short8 a1 = *(const short8*)(&Elds[(16 + n16) * ESTR + ko]);
            #pragma unroll
            for (int nt = 0; nt < 4; ++nt) {
                short8 bfr = *(const short8*)(&w1t[(size_t)(nc + nt * 16 + n16) * 256 + ko]);
                acc1[0][nt] = __builtin_amdgcn_mfma_f32_16x16x32_bf16(a0, bfr, acc1[0][nt], 0, 0, 0);
                acc1[1][nt] = __builtin_amdgcn_mfma_f32_16x16x32_bf16(a1, bfr, acc1[1][nt], 0, 0, 0);
            }
        }
        #pragma unroll
        for (int mt = 0; mt < 2; ++mt)
            #pragma unroll
            for (int nt = 0; nt < 4; ++nt) {
                int col = nc + nt * 16 + n16;
                #pragma unroll
                for (int r = 0; r < 4; ++r) {
                    int row = mt * 16 + quad * 4 + r;
                    Hlds[row * ESTR + col] = f2b(fmaxf(acc1[mt][nt][r], 0.f));
                }
            }
    }
    __syncthreads();

    {
        int nc2 = wave * 128;
        f32x4 acc2[2][8];
        #pragma unroll
        for (int mt = 0; mt < 2; ++mt)
            #pragma unroll
            for (int nt = 0; nt < 8; ++nt) acc2[mt][nt] = (f32x4){0.f, 0.f, 0.f, 0.f};
        #pragma unroll
        for (int k8 = 0; k8 < 8; ++k8) {
            int ko = k8 * 32 + quad * 8;
            short8 a0 = *(const short8*)(&Hlds[(n16) * ESTR + ko]);
            short8 a1 = *(const short8*)(&Hlds[(16 + n16) * ESTR + ko]);
            #pragma unroll
            for (int nt = 0; nt < 8; ++nt) {
                short8 bfr = *(const short8*)(&w2t[(size_t)(nc2 + nt * 16 + n16) * 256 + ko]);
                acc2[0][nt] = __builtin_amdgcn_mfma_f32_16x16x32_bf16(a0, bfr, acc2[0][nt], 0, 0, 0);
                acc2[1][nt] = __builtin_amdgcn_mfma_f32_16x16x32_bf16(a1, bfr, acc2[1][nt], 0, 0, 0);
            }
        }
        #pragma unroll
        for (int mt = 0; mt < 2; ++mt)
            #pragma unroll
            for (int nt = 0; nt < 8; ++nt) {
                f32x4 a = acc2[mt][nt];
                float v = fmaxf(fmaxf(a[0], a[1]), fmaxf(a[2], a[3]));
                float o = fmaxf(v, __shfl_xor(v, 16, 64));
                int col = nc2 + nt * 16 + n16;
                if (quad == 0)
                    x3[(size_t)(P0 + mt * 2) * 512 + col] = o + b2f[col];
                else if (quad == 2)
                    x3[(size_t)(P0 + mt * 2 + 1) * 512 + col] = o + b2f[col];
            }
    }
}

// ---------------- shared MLP + hij via bf16 MFMA, fully fused ----------------
// Block = 32 points. X[32][672]bf16 -> G1(672->256,relu) -> H[32][256]bf16 ->
// G2(256->128,+bias) -> sf f32 + S[32][128]bf16 -> G3(128->256) -> hi|hj f32.
#define XSTR 680   // 672+8 bf16; 1360B rows (16B mult; dw-offset 20 mod 32 -> 2-way free)
#define SSTR 136   // 128+8
__global__ __launch_bounds__(256) void sm_mfma_kernel(
        const float* __restrict__ x1, const float* __restrict__ x2,
        const float* __restrict__ x3,
        const ushort* __restrict__ w1t, const ushort* __restrict__ w2t,
        const ushort* __restrict__ ecw1t,
        const float* __restrict__ b1f, const float* __restrict__ b2f,
        float* __restrict__ sf, float* __restrict__ hi, float* __restrict__ hj) {
    __shared__ ushort Xlds[32 * XSTR];
    __shared__ ushort Hlds[32 * ESTR];
    __shared__ ushort Slds[32 * SSTR];
    int tid = threadIdx.x;
    int P0 = blockIdx.x * 32;

    // ---- stage concat[x1,x2,x3] -> bf16 rows
    {
        int row = tid >> 3, cseg = tid & 7;
        int p = P0 + row;
        bool ok = p < NB * NP;
        #pragma unroll
        for (int k = 0; k < 21; ++k) {
            int c = cseg * 4 + k * 32;
            float4 v = make_float4(0.f, 0.f, 0.f, 0.f);
            if (ok) {
                if (c < 32) v = *(const float4*)(x1 + (size_t)p * 32 + c);
                else if (c < 160) v = *(const float4*)(x2 + (size_t)p * 128 + (c - 32));
                else v = *(const float4*)(x3 + (size_t)p * 512 + (c - 160));
            }
            uint lo = (uint)f2b(v.x) | ((uint)f2b(v.y) << 16);
            uint hv = (uint)f2b(v.z) | ((uint)f2b(v.w) << 16);
            *(uint2*)(&Xlds[row * XSTR + c]) = make_uint2(lo, hv);
        }
    }
    __syncthreads();

    int lane = tid & 63, wave = tid >> 6;
    int n16 = lane & 15, quad = lane >> 4;

    // ---- G1: 672 -> 256, relu
    {
        int nc = wave * 64;
        f32x4 acc[2][4];
        #pragma unroll
        for (int mt = 0; mt < 2; ++mt)
            #pragma unroll
            for (int nt = 0; nt < 4; ++nt) {
                float bv = b1f[nc + nt * 16 + n16];
                acc[mt][nt] = (f32x4){bv, bv, bv, bv};
            }
        #pragma unroll
        for (int k8 = 0; k8 < 21; ++k8) {
            int ko = k8 * 32 + quad * 8;
            short8 a0 = *(const short8*)(&Xlds[(n16) * XSTR + ko]);
            short8 a1 = *(const short8*)(&Xlds[(16 + n16) * XSTR + ko]);
            #pragma unroll
            for (int nt = 0; nt < 4; ++nt) {
                short8 bfr = *(const short8*)(&w1t[(size_t)(nc + nt * 16 + n16) * 672 + ko]);
                acc[0][nt] = __builtin_amdgcn_mfma_f32_16x16x32_bf16(a0, bfr, acc[0][nt], 0, 0, 0);
                acc[1][nt] = __builtin_amdgcn_mfma_f32_16x16x32_bf16(a1, bfr, acc[1][nt], 0, 0, 0);
            }
        }
        #pragma unroll
        for (int mt = 0; mt < 2; ++mt)
            #pragma unroll
            for (int nt = 0; nt < 4; ++nt) {
                int col = nc + nt * 16 + n16;
                #pragma unroll
                for (int r = 0; r < 4; ++r) {
                    int row = mt * 16 + quad * 4 + r;
                    Hlds[row * ESTR + col] = f2b(fmaxf(acc[mt][nt][r], 0.f));
                }
            }
    }
    __syncthreads();

    // ---- G2: 256 -> 128, +bias; write sf f32 + Slds bf16
    {
        int nc = wave * 32;
        f32x4 acc[2][2];
        #pragma unroll
        for (int mt = 0; mt < 2; ++mt)
            #pragma unroll
            for (int nt = 0; nt < 2; ++nt) {
                float bv = b2f[nc + nt * 16 + n16];
                acc[mt][nt] = (f32x4){bv, bv, bv, bv};
            }
        #pragma unroll
        for (int k8 = 0; k8 < 8; ++k8) {
            int ko = k8 * 32 + quad * 8;
            short8 a0 = *(const short8*)(&Hlds[(n16) * ESTR + ko]);
            short8 a1 = *(const short8*)(&Hlds[(16 + n16) * ESTR + ko]);
            #pragma unroll
            for (int nt = 0; nt < 2; ++nt) {
                short8 bfr = *(const short8*)(&w2t[(size_t)(nc + nt * 16 + n16) * 256 + ko]);
                acc[0][nt] = __builtin_amdgcn_mfma_f32_16x16x32_bf16(a0, bfr, acc[0][nt], 0, 0, 0);
                acc[1][nt] = __builtin_amdgcn_mfma_f32_16x16x32_bf16(a1, bfr, acc[1][nt], 0, 0, 0);
            }
        }
        #pragma unroll
        for (int mt = 0; mt < 2; ++mt)
            #pragma unroll
            for (int nt = 0; nt < 2; ++nt) {
                int col = nc + nt * 16 + n16;
                #pragma unroll
                for (int r = 0; r < 4; ++r) {
                    int row = mt * 16 + quad * 4 + r;
                    int p = P0 + row;
                    float v = acc[mt][nt][r];
                    if (p < NB * NP) sf[(size_t)p * 128 + col] = v;
                    Slds[row * SSTR + col] = f2b(v);
                }
            }
    }
    __syncthreads();

    // ---- G3: 128 -> 256 (hi | hj)
    {
        int nc = wave * 64;
        f32x4 acc[2][4];
        #pragma unroll
        for (int mt = 0; mt < 2; ++mt)
            #pragma unroll
            for (int nt = 0; nt < 4; ++nt) acc[mt][nt] = (f32x4){0.f, 0.f, 0.f, 0.f};
        #pragma unroll
        for (int k8 = 0; k8 < 4; ++k8) {
            int ko = k8 * 32 + quad * 8;
            short8 a0 = *(const short8*)(&Slds[(n16) * SSTR + ko]);
            short8 a1 = *(const short8*)(&Slds[(16 + n16) * SSTR + ko]);
            #pragma unroll
            for (int nt = 0; nt < 4; ++nt) {
                short8 bfr = *(const short8*)(&ecw1t[(size_t)(nc + nt * 16 + n16) * 128 + ko]);
                acc[0][nt] = __builtin_amdgcn_mfma_f32_16x16x32_bf16(a0, bfr, acc[0][nt], 0, 0, 0);
                acc[1][nt] = __builtin_amdgcn_mfma_f32_16x16x32_bf16(a1, bfr, acc[1][nt], 0, 0, 0);
            }
        }
        #pragma unroll
        for (int mt = 0; mt < 2; ++mt)
            #pragma unroll
            for (int nt = 0; nt < 4; ++nt) {
                int colp = nc + nt * 16 + n16;
                float* dst = (colp < 128) ? hi : hj;
                int col = colp & 127;
                #pragma unroll
                for (int r = 0; r < 4; ++r) {
                    int row = mt * 16 + quad * 4 + r;
                    int p = P0 + row;
                    if (p < NB * NP) dst[(size_t)p * 128 + col] = acc[mt][nt][r];
                }
            }
    }
}

// ---------------- global max pool, two-stage ----------------
__global__ void gmax1_kernel(const float* __restrict__ sf, float* __restrict__ part) {
    int m = blockIdx.x;
    int b = m / 25, ch = m % 25, o = threadIdx.x;
    float v = -INFINITY;
    int n0 = ch * 40;
    for (int n = n0; n < n0 + 40; ++n)
        v = fmaxf(v, sf[((size_t)b * NP + n) * 128 + o]);
    part[(size_t)m * 128 + o] = v;
}

__global__ void gmax2_kernel(const float* __restrict__ part, float* __restrict__ g) {
    int b = blockIdx.x, o = threadIdx.x;
    float v = -INFINITY;
    for (int ch = 0; ch < 25; ++ch)
        v = fmaxf(v, part[((size_t)b * 25 + ch) * 128 + o]);
    g[b * 128 + o] = v;
}

// ---------------- hg = g @ W[256:384] + b1 ----------------
__global__ void hg_kernel(const float* __restrict__ g, const float* __restrict__ w1,
                          const float* __restrict__ b1, float* __restrict__ hg) {
    int b = blockIdx.x, o = threadIdx.x;
    float acc = b1[o];
    for (int c = 0; c < 128; ++c) acc += g[b * 128 + c] * w1[(256 + c) * 128 + o];
    hg[b * 128 + o] = acc;
}

// ---------------- pairwise scorer over 32x32 tiles of (i,j), i<j ----------------
__global__ void pair_kernel(const float* __restrict__ hi, const float* __restrict__ hj,
                            const float* __restrict__ hg,
                            const float* __restrict__ w2, const float* __restrict__ b2,
                            void* __restrict__ out, const int* __restrict__ flag) {
    int j0 = blockIdx.x * 32, i0 = blockIdx.y * 32, b = blockIdx.z;
    if (j0 + 31 <= i0) return;
    __shared__ float hit[32][129];
    __shared__ float hjt[32][129];
    __shared__ float hgs[128];
    __shared__ float w2s[128];
    int tid = threadIdx.x;
    if (tid < 128) {
        hgs[tid] = hg[b * 128 + tid];
        w2s[tid] = w2[tid];
    }
    for (int t = tid; t < 32 * 128; t += 256) {
        int r = t >> 7, c = t & 127;
        int i = i0 + r, j = j0 + r;
        hit[r][c] = (i < NP) ? hi[((size_t)b * NP + i) * 128 + c] : 0.f;
        hjt[r][c] = (j < NP) ? hj[((size_t)b * NP + j) * 128 + c] : 0.f;
    }
    __syncthreads();
    float bb = b2[0];
    int f = flag[0];
    int tj = tid & 31;
    int ti0 = tid >> 5;
    int j = j0 + tj;
    float acc[4] = {0.f, 0.f, 0.f, 0.f};
    for (int o = 0; o < 128; ++o) {
        float hv = hjt[tj][o] + hgs[o];
        float wv = w2s[o];
        acc[0] += fmaxf(hit[ti0][o] + hv, 0.f) * wv;
        acc[1] += fmaxf(hit[ti0 + 8][o] + hv, 0.f) * wv;
        acc[2] += fmaxf(hit[ti0 + 16][o] + hv, 0.f) * wv;
        acc[3] += fmaxf(hit[ti0 + 24][o] + hv, 0.f) * wv;
    }
    for (int r = 0; r < 4; ++r) {
        int i = i0 + ti0 + 8 * r;
        if (i < j && j < NP) {
            size_t p = (size_t)i * (NP - 1) - (size_t)i * (i - 1) / 2 + (j - i - 1);
            float mo = acc[r] + bb;
            float pr = 1.f / (1.f + expf(-mo));
            size_t idx0 = (size_t)b * PPAIR + p;
            size_t idx1 = (size_t)NB * PPAIR + idx0;
            if (f) {
                ((float*)out)[idx0] = pr;
                ((float*)out)[idx1] = mo;
            } else {
                ((bf16*)out)[idx0] = __float2bfloat16(pr);
                ((bf16*)out)[idx1] = __float2bfloat16(mo);
            }
        }
    }
}

extern "C" void kernel_launch(void* const* d_in, const int* in_sizes, int n_in,
                              void* d_out, int out_size, void* d_ws, size_t ws_size,
                              hipStream_t stream) {
    float* ws = (float*)d_ws;
    float* posf = ws + OFF_POS;
    float* x1   = ws + OFF_X1;
    float* x2   = ws + OFF_X2;
    float* x3   = ws + OFF_X3;
    float* sf   = ws + OFF_SF;
    float* g    = ws + OFF_G;
    float* hi   = ws + OFF_HI;
    float* hj   = ws + OFF_HJ;
    float* hgb  = ws + OFF_HG;
    int*   flag = (int*)(ws + OFF_FLAG);
    int*   nidx = (int*)(ws + OFF_NIDX);
    float* d2   = ws + OFF_D2;
    float* gp   = ws + OFF_GP;
    ushort* w1t = (ushort*)(ws + OFF_W1T);
    ushort* w2t = (ushort*)(ws + OFF_W2T);
    ushort* smw1t = (ushort*)(ws + OFF_SMW1T);
    ushort* smw2t = (ushort*)(ws + OFF_SMW2T);
    ushort* ecw1t = (ushort*)(ws + OFF_ECW1T);

    // 1) detect input dtype (bf16 vs f32) on-device
    detect_kernel<<<1, 256, 0, stream>>>(d_in[0], flag);

    // 2) convert all inputs to f32 workspace; transpose/bf16 MFMA weights
    InPtrs ip;
    for (int i = 0; i < 21; ++i) ip.p[i] = d_in[i];
    dim3 cgrid(672, 21);
    cvt_all_kernel<<<cgrid, 256, 0, stream>>>(ip, ws, flag);
    dim3 wgrid(672, 5);
    wtrans_kernel<<<wgrid, 256, 0, stream>>>(ws, w1t, w2t, smw1t, smw2t, ecw1t);

    dim3 dgrid(16, 16, NB);
    dim3 sgrid(NP / 4, NB);

    // 3) EdgeConv 1 (C=3 -> 32)
    dist_kernel<3><<<dgrid, 256, 0, stream>>>(posf, d2);
    select_kernel<<<sgrid, 256, 0, stream>>>(d2, nidx);
    edgeconv_kernel<3, 16, 32><<<NB * NP, 256, 0, stream>>>(
        posf, nidx, ws + OFF_C1W1, ws + OFF_C1B1, ws + OFF_C1W2, ws + OFF_C1B2, x1);

    // 4) EdgeConv 2 (C=32 -> 128)
    dist_kernel<32><<<dgrid, 256, 0, stream>>>(x1, d2);
    select_kernel<<<sgrid, 256, 0, stream>>>(d2, nidx);
    edgeconv_kernel<32, 64, 128><<<NB * NP, 256, 0, stream>>>(
        x1, nidx, ws + OFF_C2W1, ws + OFF_C2B1, ws + OFF_C2W2, ws + OFF_C2B2, x2);

    // 5) EdgeConv 3 (C=128 -> 512) via MFMA
    dist_kernel<128><<<dgrid, 256, 0, stream>>>(x2, d2);
    select_kernel<<<sgrid, 256, 0, stream>>>(d2, nidx);
    ec3_mfma_kernel<<<NB * NP / 4, 256, 0, stream>>>(
        x2, nidx, w1t, w2t, ws + OFF_C3B1, ws + OFF_C3B2, x3);

    // 6) shared MLP + hij via MFMA -> sf, hi, hj
    sm_mfma_kernel<<<(NB * NP + 31) / 32, 256, 0, stream>>>(
        x1, x2, x3, smw1t, smw2t, ecw1t, ws + OFF_SMB1, ws + OFF_SMB2, sf, hi, hj);

    // 7) global max pool (two-stage)
    gmax1_kernel<<<NB * 25, 128, 0, stream>>>(sf, gp);
    gmax2_kernel<<<NB, 128, 0, stream>>>(gp, g);

    // 8) hg projection
    hg_kernel<<<NB, 128, 0, stream>>>(g, ws + OFF_ECW1, ws + OFF_ECB1, hgb);

    // 9) pairwise scorer
    dim3 pgrid(32, 32, NB);
    pair_kernel<<<pgrid, 256, 0, stream>>>(hi, hj, hgb, ws + OFF_ECW2, ws + OFF_ECB2,
                                           d_out, flag);
}

// Round 7
// 340.612 us; speedup vs baseline: 2.1133x; 1.0455x over previous
//
#include <hip/hip_runtime.h>
#include <hip/hip_bf16.h>
#include <cmath>

// Problem constants (B=2, N=1000, k=8 from reference)
#define NB 2
#define NP 1000
#define KNN 8
#define PPAIR 499500  // N*(N-1)/2

typedef __hip_bfloat16 bf16;
typedef unsigned long long u64;
typedef unsigned short ushort;
typedef unsigned int uint;
typedef __attribute__((ext_vector_type(8))) short short8;
typedef __attribute__((ext_vector_type(4))) float f32x4;

__device__ __forceinline__ float b2f(bf16 v) { return __bfloat162float(v); }
// f32 -> bf16 bits, round-to-nearest-even
__device__ __forceinline__ ushort f2b(float f) {
    uint x = __float_as_uint(f);
    return (ushort)((x + 0x7FFFu + ((x >> 16) & 1u)) >> 16);
}

// Workspace layout (float offsets), all 16B-aligned
#define OFF_POS    0
#define OFF_C1W1   6000
#define OFF_C1B1   6096
#define OFF_C1W2   6112
#define OFF_C1B2   6624
#define OFF_C2W1   6656
#define OFF_C2B1   10752
#define OFF_C2W2   10816
#define OFF_C2B2   19008
#define OFF_C3W1   19136
#define OFF_C3B1   84672
#define OFF_C3W2   84928
#define OFF_C3B2   216000
#define OFF_SMW1   216512
#define OFF_SMB1   388544
#define OFF_SMW2   388800
#define OFF_SMB2   421568
#define OFF_ECW1   421696
#define OFF_ECB1   470848
#define OFF_ECW2   470976
#define OFF_ECB2   471104
#define OFF_X1     471112
#define OFF_X2     535112
#define OFF_X3     791112
#define OFF_SF     1815112
#define OFF_G      2071112
#define OFF_HI     2071368
#define OFF_HJ     2327368
#define OFF_HG     2583368
#define OFF_FLAG   2583624   // int
#define OFF_NIDX   2583632   // 16000 ints
#define OFF_GP     2599632   // 50*128 partial max
#define OFF_W1T    2606032   // ec3 W1T 256x256 bf16 (32768 f32)
#define OFF_W2T    2638800   // ec3 W2T 512x256 bf16 (65536 f32)
#define OFF_SMW1T  2704336   // sm W1T 256x672 bf16 (86016 f32)
#define OFF_SMW2T  2790352   // sm W2T 128x256 bf16 (16384 f32)
#define OFF_ECW1T  2806736   // hij WT 256x128 bf16 (16384 f32)

// ---------------- dtype detection ----------------
__global__ void detect_kernel(const void* pos, int* flag) {
    __shared__ float red[256];
    const unsigned short* p = (const unsigned short*)pos;
    float m = 0.f;
    for (int t = threadIdx.x; t < 6000; t += 256) {
        unsigned int u = ((unsigned int)p[t]) << 16;
        float v = fabsf(__uint_as_float(u));
        if (!isfinite(v)) v = 1e30f;
        m = fmaxf(m, v);
    }
    red[threadIdx.x] = m;
    __syncthreads();
    for (int s = 128; s > 0; s >>= 1) {
        if (threadIdx.x < s) red[threadIdx.x] = fmaxf(red[threadIdx.x], red[threadIdx.x + s]);
        __syncthreads();
    }
    if (threadIdx.x == 0) flag[0] = (red[0] > 1e6f) ? 1 : 0;
}

// ---------------- convert all 21 inputs to f32 workspace ----------------
struct InPtrs { const void* p[21]; };

__global__ void cvt_all_kernel(InPtrs in, float* ws, const int* flag) {
    const int sizes[21] = {6000, 96, 16, 512, 32, 4096, 64, 8192, 128,
                           65536, 256, 131072, 512, 172032, 256, 32768, 128,
                           49152, 128, 128, 1};
    const int offs[21] = {OFF_POS, OFF_C1W1, OFF_C1B1, OFF_C1W2, OFF_C1B2,
                          OFF_C2W1, OFF_C2B1, OFF_C2W2, OFF_C2B2,
                          OFF_C3W1, OFF_C3B1, OFF_C3W2, OFF_C3B2,
                          OFF_SMW1, OFF_SMB1, OFF_SMW2, OFF_SMB2,
                          OFF_ECW1, OFF_ECB1, OFF_ECW2, OFF_ECB2};
    int which = blockIdx.y;
    int n = sizes[which];
    int t = blockIdx.x * 256 + threadIdx.x;
    if (t >= n) return;
    float v;
    if (flag[0]) v = ((const float*)in.p[which])[t];
    else v = b2f(((const bf16*)in.p[which])[t]);
    ws[offs[which] + t] = v;
}

// ---------------- transpose+bf16 weights for all MFMA kernels ----------------
__global__ void wtrans_kernel(const float* __restrict__ ws, ushort* __restrict__ w1t,
                              ushort* __restrict__ w2t, ushort* __restrict__ smw1t,
                              ushort* __restrict__ smw2t, ushort* __restrict__ ecw1t) {
    int t = blockIdx.x * 256 + threadIdx.x;
    int y = blockIdx.y;
    if (y == 0) {
        if (t < 65536) {            // ec3 W1 [c=256][h=256] -> [h][c]
            int h = t >> 8, c = t & 255;
            w1t[t] = f2b(ws[OFF_C3W1 + c * 256 + h]);
        }
    } else if (y == 1) {
        if (t < 131072) {           // ec3 W2 [h=256][o=512] -> [o][h]
            int o = t >> 8, h = t & 255;
            w2t[t] = f2b(ws[OFF_C3W2 + h * 512 + o]);
        }
    } else if (y == 2) {
        if (t < 172032) {           // sm W1 [c=672][h=256] -> [h][c]
            int h = t / 672, c = t - h * 672;
            smw1t[t] = f2b(ws[OFF_SMW1 + c * 256 + h]);
        }
    } else if (y == 3) {
        if (t < 32768) {            // sm W2 [h=256][o=128] -> [o][h]
            int o = t >> 8, h = t & 255;
            smw2t[t] = f2b(ws[OFF_SMW2 + h * 128 + o]);
        }
    } else {
        if (t < 32768) {            // ec W1[:256] -> [o'][c] (o'>=128 -> hj cols)
            int op = t >> 7, c = t & 127;
            float v = (op < 128) ? ws[OFF_ECW1 + c * 128 + op]
                                 : ws[OFF_ECW1 + (128 + c) * 128 + (op - 128)];
            ecw1t[t] = f2b(v);
        }
    }
}

// ---------------- fused kNN: dist + top-8 select, no global d2 ----------------
// Block = 8 queries x 256 threads. 32-lane group per query; lane handles
// j = j0+jcol and j0+jcol+32 per 64-point chunk. Distances -> packed u64
// (d2_bits<<32 | j) -> branchless sorted top-8 insert -> 5-stage shfl_xor
// bitonic merge across the 32-lane group (same verified network as before).
__device__ __forceinline__ void ce(u64& a, u64& b) {
    u64 lo = a < b ? a : b;
    u64 hi = a < b ? b : a;
    a = lo; b = hi;
}

__device__ __forceinline__ void ins8(u64 (&best)[KNN], u64 cand) {
    u64 cur = cand;
    #pragma unroll
    for (int r = 0; r < KNN; ++r) {
        u64 lo = best[r] < cur ? best[r] : cur;
        u64 hi = best[r] < cur ? cur : best[r];
        best[r] = lo; cur = hi;
    }
}

template <int C>
__global__ __launch_bounds__(256) void knn_fused_kernel(const float* __restrict__ x,
                                                        int* __restrict__ nidx) {
    constexpr int CP = (C + 3) & ~3;
    constexpr int PSTR = CP + 4;      // dword stride: mult of 4 (16B align), %8==0? no: CP%8==0 -> PSTR%8==4
    __shared__ float Qs[8 * PSTR];
    __shared__ float Ps[64 * PSTR];
    int tid = threadIdx.x;
    int b = blockIdx.y;
    int i0 = blockIdx.x * 8;
    int q = tid >> 5;                 // 0..7, 32-lane group per query (wave-aligned)
    int jcol = tid & 31;

    // stage Q rows (8 x CP), zero-pad
    for (int idx = tid; idx < 8 * CP; idx += 256) {
        int row = idx / CP, c = idx % CP;
        int i = i0 + row;
        Qs[row * PSTR + c] = (c < C && i < NP) ? x[((size_t)b * NP + i) * C + c] : 0.f;
    }

    u64 best[KNN];
    #pragma unroll
    for (int r = 0; r < KNN; ++r) best[r] = ~0ull;

    for (int jc = 0; jc < 16; ++jc) {
        int j0 = jc * 64;
        __syncthreads();              // protect Ps from previous iteration's readers
        if (C % 4 == 0) {
            for (int idx = tid; idx < 64 * (C / 4); idx += 256) {
                int row = idx / (C / 4), c4 = idx % (C / 4);
                int j = j0 + row;
                float4 v = make_float4(0.f, 0.f, 0.f, 0.f);
                if (j < NP) v = *(const float4*)(x + ((size_t)b * NP + j) * C + c4 * 4);
                *(float4*)(&Ps[row * PSTR + c4 * 4]) = v;
            }
        } else {
            for (int idx = tid; idx < 64 * CP; idx += 256) {
                int row = idx / CP, c = idx % CP;
                int j = j0 + row;
                Ps[row * PSTR + c] = (c < C && j < NP) ? x[((size_t)b * NP + j) * C + c] : 0.f;
            }
        }
        __syncthreads();
        float d0 = 0.f, d1 = 0.f;
        #pragma unroll
        for (int c4 = 0; c4 < CP / 4; ++c4) {
            float4 qv = *(const float4*)(&Qs[q * PSTR + c4 * 4]);
            float4 p0 = *(const float4*)(&Ps[jcol * PSTR + c4 * 4]);
            float4 p1 = *(const float4*)(&Ps[(jcol + 32) * PSTR + c4 * 4]);
            float t;
            t = qv.x - p0.x; d0 += t * t;  t = qv.y - p0.y; d0 += t * t;
            t = qv.z - p0.z; d0 += t * t;  t = qv.w - p0.w; d0 += t * t;
            t = qv.x - p1.x; d1 += t * t;  t = qv.y - p1.y; d1 += t * t;
            t = qv.z - p1.z; d1 += t * t;  t = qv.w - p1.w; d1 += t * t;
        }
        int ja = j0 + jcol, jb = j0 + jcol + 32;
        u64 ca = (ja < NP) ? ((((u64)__float_as_uint(d0)) << 32) | (unsigned)ja) : ~0ull;
        u64 cb = (jb < NP) ? ((((u64)__float_as_uint(d1)) << 32) | (unsigned)jb) : ~0ull;
        ins8(best, ca);
        ins8(best, cb);
    }

    // bitonic butterfly merge across the 32-lane group
    #pragma unroll
    for (int m = 1; m < 32; m <<= 1) {
        u64 other[KNN];
        #pragma unroll
        for (int r = 0; r < KNN; ++r)
            other[r] = __shfl_xor((unsigned long long)best[r], m, 64);
        u64 v[KNN];
        #pragma unroll
        for (int r = 0; r < KNN; ++r)
            v[r] = best[r] < other[7 - r] ? best[r] : other[7 - r];
        ce(v[0], v[4]); ce(v[1], v[5]); ce(v[2], v[6]); ce(v[3], v[7]);
        ce(v[0], v[2]); ce(v[1], v[3]); ce(v[4], v[6]); ce(v[5], v[7]);
        ce(v[0], v[1]); ce(v[2], v[3]); ce(v[4], v[5]); ce(v[6], v[7]);
        #pragma unroll
        for (int r = 0; r < KNN; ++r) best[r] = v[r];
    }

    int i = i0 + q;
    if (jcol == 0 && i < NP) {
        #pragma unroll
        for (int r = 0; r < KNN; ++r)
            nidx[((size_t)b * NP + i) * KNN + r] = (int)(best[r] & 0xffffffffu);
    }
}

// ---------------- fused EdgeConv (f32, small layers 1 & 2) ----------------
template <int CIN, int CHID, int COUT>
__global__ void edgeconv_kernel(const float* __restrict__ x, const int* __restrict__ nidx,
                                const float* __restrict__ w1, const float* __restrict__ b1,
                                const float* __restrict__ w2, const float* __restrict__ b2,
                                float* __restrict__ y) {
    int bi = blockIdx.x;
    int b = bi / NP;
    __shared__ float xi[CIN];
    __shared__ float dx[KNN][CIN];
    __shared__ __align__(16) float hid[CHID][12];
    __shared__ int nb[KNN];
    int tid = threadIdx.x;
    if (tid < KNN) nb[tid] = nidx[bi * KNN + tid];
    for (int c = tid; c < CIN; c += 256) xi[c] = x[(size_t)bi * CIN + c];
    __syncthreads();
    for (int t = tid; t < KNN * CIN; t += 256) {
        int k = t / CIN, c = t % CIN;
        dx[k][c] = x[((size_t)b * NP + nb[k]) * CIN + c] - xi[c];
    }
    __syncthreads();
    for (int h = tid; h < CHID; h += 256) {
        float common = b1[h];
        for (int c = 0; c < CIN; ++c) common += xi[c] * w1[c * CHID + h];
        float acc[KNN];
        for (int k = 0; k < KNN; ++k) acc[k] = common;
        for (int c = 0; c < CIN; ++c) {
            float wv = w1[(CIN + c) * CHID + h];
            for (int k = 0; k < KNN; ++k) acc[k] += dx[k][c] * wv;
        }
        for (int k = 0; k < KNN; ++k) hid[h][k] = fmaxf(acc[k], 0.f);
    }
    __syncthreads();
    for (int o = tid; o < COUT; o += 256) {
        float acc[KNN];
        for (int k = 0; k < KNN; ++k) acc[k] = 0.f;
        for (int h = 0; h < CHID; ++h) {
            float wv = w2[h * COUT + o];
            float4 h0 = *(const float4*)&hid[h][0];
            float4 h1 = *(const float4*)&hid[h][4];
            acc[0] += h0.x * wv; acc[1] += h0.y * wv; acc[2] += h0.z * wv; acc[3] += h0.w * wv;
            acc[4] += h1.x * wv; acc[5] += h1.y * wv; acc[6] += h1.z * wv; acc[7] += h1.w * wv;
        }
        float m = acc[0];
        for (int k = 1; k < KNN; ++k) m = fmaxf(m, acc[k]);
        y[(size_t)bi * COUT + o] = m + b2[o];
    }
}

// ---------------- EdgeConv-3 via bf16 MFMA, fully fused ----------------
// MFMA 16x16x32_bf16: A[m=lane&15][k=quad*8+j]; C/D col=lane&15,row=quad*4+reg.
#define ESTR 264   // LDS row stride (bf16 elems)
__global__ __launch_bounds__(256) void ec3_mfma_kernel(
        const float* __restrict__ x2, const int* __restrict__ nidx,
        const ushort* __restrict__ w1t, const ushort* __restrict__ w2t,
        const float* __restrict__ b1f, const float* __restrict__ b2f,
        float* __restrict__ x3) {
    __shared__ ushort Elds[32 * ESTR];
    __shared__ ushort Hlds[32 * ESTR];
    int tid = threadIdx.x;
    int P0 = blockIdx.x * 4;

    {
        int e = tid >> 3, seg = tid & 7;
        int bi = P0 + (e >> 3), k = e & 7;
        int b = bi / NP;
        int nb = nidx[bi * KNN + k];
        const float* xi = x2 + (size_t)bi * 128;
        const float* xj = x2 + ((size_t)b * NP + nb) * 128;
        int c0 = seg * 16;
        #pragma unroll
        for (int c = c0; c < c0 + 16; c += 4) {
            float4 a = *(const float4*)(xi + c);
            float4 q = *(const float4*)(xj + c);
            uint lo = (uint)f2b(a.x) | ((uint)f2b(a.y) << 16);
            uint hi = (uint)f2b(a.z) | ((uint)f2b(a.w) << 16);
            *(uint2*)(&Elds[e * ESTR + c]) = make_uint2(lo, hi);
            lo = (uint)f2b(q.x - a.x) | ((uint)f2b(q.y - a.y) << 16);
            hi = (uint)f2b(q.z - a.z) | ((uint)f2b(q.w - a.w) << 16);
            *(uint2*)(&Elds[e * ESTR + 128 + c]) = make_uint2(lo, hi);
        }
    }
    __syncthreads();

    int lane = tid & 63, wave = tid >> 6;
    int n16 = lane & 15, quad = lane >> 4;

    {
        int nc = wave * 64;
        f32x4 acc1[2][4];
        #pragma unroll
        for (int mt = 0; mt < 2; ++mt)
            #pragma unroll
            for (int nt = 0; nt < 4; ++nt) {
                float bv = b1f[nc + nt * 16 + n16];
                acc1[mt][nt] = (f32x4){bv, bv, bv, bv};
            }
        #pragma unroll
        for (int k8 = 0; k8 < 8; ++k8) {
            int ko = k8 * 32 + quad * 8;
            short8 a0 = *(const short8*)(&Elds[(n16) * ESTR + ko]);
            short8 a1 = *(const short8*)(&Elds[(16 + n16) * ESTR + ko]);
            #pragma unroll
            for (int nt = 0; nt < 4; ++nt) {
                short8 bfr = *(const short8*)(&w1t[(size_t)(nc + nt * 16 + n16) * 256 + ko]);
                acc1[0][nt] = __builtin_amdgcn_mfma_f32_16x16x32_bf16(a0, bfr, acc1[0][nt], 0, 0, 0);
                acc1[1][nt] = __builtin_amdgcn_mfma_f32_16x16x32_bf16(a1, bfr, acc1[1][nt], 0, 0, 0);
            }
        }
        #pragma unroll
        for (int mt = 0; mt < 2; ++mt)
            #pragma unroll
            for (int nt = 0; nt < 4; ++nt) {
                int col = nc + nt * 16 + n16;
                #pragma unroll
                for (int r = 0; r < 4; ++r) {
                    int row = mt * 16 + quad * 4 + r;
                    Hlds[row * ESTR + col] = f2b(fmaxf(acc1[mt][nt][r], 0.f));
                }
            }
    }
    __syncthreads();

    {
        int nc2 = wave * 128;
        f32x4 acc2[2][8];
        #pragma unroll
        for (int mt = 0; mt < 2; ++mt)
            #pragma unroll
            for (int nt = 0; nt < 8; ++nt) acc2[mt][nt] = (f32x4){0.f, 0.f, 0.f, 0.f};
        #pragma unroll
        for (int k8 = 0; k8 < 8; ++k8) {
            int ko = k8 * 32 + quad * 8;
            short8 a0 = *(const short8*)(&Hlds[(n16) * ESTR + ko]);
            short8 a1 = *(const short8*)(&Hlds[(16 + n16) * ESTR + ko]);
            #pragma unroll
            for (int nt = 0; nt < 8; ++nt) {
                short8 bfr = *(const short8*)(&w2t[(size_t)(nc2 + nt * 16 + n16) * 256 + ko]);
                acc2[0][nt] = __builtin_amdgcn_mfma_f32_16x16x32_bf16(a0, bfr, acc2[0][nt], 0, 0, 0);
                acc2[1][nt] = __builtin_amdgcn_mfma_f32_16x16x32_bf16(a1, bfr, acc2[1][nt], 0, 0, 0);
            }
        }
        #pragma unroll
        for (int mt = 0; mt < 2; ++mt)
            #pragma unroll
            for (int nt = 0; nt < 8; ++nt) {
                f32x4 a = acc2[mt][nt];
                float v = fmaxf(fmaxf(a[0], a[1]), fmaxf(a[2], a[3]));
                float o = fmaxf(v, __shfl_xor(v, 16, 64));
                int col = nc2 + nt * 16 + n16;
                if (quad == 0)
                    x3[(size_t)(P0 + mt * 2) * 512 + col] = o + b2f[col];
                else if (quad == 2)
                    x3[(size_t)(P0 + mt * 2 + 1) * 512 + col] = o + b2f[col];
            }
    }
}

// ---------------- shared MLP + hij via bf16 MFMA, fully fused ----------------
#define XSTR 680   // 672+8 bf16
#define SSTR 136   // 128+8
__global__ __launch_bounds__(256) void sm_mfma_kernel(
        const float* __restrict__ x1, const float* __restrict__ x2,
        const float* __restrict__ x3,
        const ushort* __restrict__ w1t, const ushort* __restrict__ w2t,
        const ushort* __restrict__ ecw1t,
        const float* __restrict__ b1f, const float* __restrict__ b2f,
        float* __restrict__ sf, float* __restrict__ hi, float* __restrict__ hj) {
    __shared__ ushort Xlds[32 * XSTR];
    __shared__ ushort Hlds[32 * ESTR];
    __shared__ ushort Slds[32 * SSTR];
    int tid = threadIdx.x;
    int P0 = blockIdx.x * 32;

    {
        int row = tid >> 3, cseg = tid & 7;
        int p = P0 + row;
        bool ok = p < NB * NP;
        #pragma unroll
        for (int k = 0; k < 21; ++k) {
            int c = cseg * 4 + k * 32;
            float4 v = make_float4(0.f, 0.f, 0.f, 0.f);
            if (ok) {
                if (c < 32) v = *(const float4*)(x1 + (size_t)p * 32 + c);
                else if (c < 160) v = *(const float4*)(x2 + (size_t)p * 128 + (c - 32));
                else v = *(const float4*)(x3 + (size_t)p * 512 + (c - 160));
            }
            uint lo = (uint)f2b(v.x) | ((uint)f2b(v.y) << 16);
            uint hv = (uint)f2b(v.z) | ((uint)f2b(v.w) << 16);
            *(uint2*)(&Xlds[row * XSTR + c]) = make_uint2(lo, hv);
        }
    }
    __syncthreads();

    int lane = tid & 63, wave = tid >> 6;
    int n16 = lane & 15, quad = lane >> 4;

    {
        int nc = wave * 64;
        f32x4 acc[2][4];
        #pragma unroll
        for (int mt = 0; mt < 2; ++mt)
            #pragma unroll
            for (int nt = 0; nt < 4; ++nt) {
                float bv = b1f[nc + nt * 16 + n16];
                acc[mt][nt] = (f32x4){bv, bv, bv, bv};
            }
        #pragma unroll
        for (int k8 = 0; k8 < 21; ++k8) {
            int ko = k8 * 32 + quad * 8;
            short8 a0 = *(const short8*)(&Xlds[(n16) * XSTR + ko]);
            short8 a1 = *(const short8*)(&Xlds[(16 + n16) * XSTR + ko]);
            #pragma unroll
            for (int nt = 0; nt < 4; ++nt) {
                short8 bfr = *(const short8*)(&w1t[(size_t)(nc + nt * 16 + n16) * 672 + ko]);
                acc[0][nt] = __builtin_amdgcn_mfma_f32_16x16x32_bf16(a0, bfr, acc[0][nt], 0, 0, 0);
                acc[1][nt] = __builtin_amdgcn_mfma_f32_16x16x32_bf16(a1, bfr, acc[1][nt], 0, 0, 0);
            }
        }
        #pragma unroll
        for (int mt = 0; mt < 2; ++mt)
            #pragma unroll
            for (int nt = 0; nt < 4; ++nt) {
                int col = nc + nt * 16 + n16;
                #pragma unroll
                for (int r = 0; r < 4; ++r) {
                    int row = mt * 16 + quad * 4 + r;
                    Hlds[row * ESTR + col] = f2b(fmaxf(acc[mt][nt][r], 0.f));
                }
            }
    }
    __syncthreads();

    {
        int nc = wave * 32;
        f32x4 acc[2][2];
        #pragma unroll
        for (int mt = 0; mt < 2; ++mt)
            #pragma unroll
            for (int nt = 0; nt < 2; ++nt) {
                float bv = b2f[nc + nt * 16 + n16];
                acc[mt][nt] = (f32x4){bv, bv, bv, bv};
            }
        #pragma unroll
        for (int k8 = 0; k8 < 8; ++k8) {
            int ko = k8 * 32 + quad * 8;
            short8 a0 = *(const short8*)(&Hlds[(n16) * ESTR + ko]);
            short8 a1 = *(const short8*)(&Hlds[(16 + n16) * ESTR + ko]);
            #pragma unroll
            for (int nt = 0; nt < 2; ++nt) {
                short8 bfr = *(const short8*)(&w2t[(size_t)(nc + nt * 16 + n16) * 256 + ko]);
                acc[0][nt] = __builtin_amdgcn_mfma_f32_16x16x32_bf16(a0, bfr, acc[0][nt], 0, 0, 0);
                acc[1][nt] = __builtin_amdgcn_mfma_f32_16x16x32_bf16(a1, bfr, acc[1][nt], 0, 0, 0);
            }
        }
        #pragma unroll
        for (int mt = 0; mt < 2; ++mt)
            #pragma unroll
            for (int nt = 0; nt < 2; ++nt) {
                int col = nc + nt * 16 + n16;
                #pragma unroll
                for (int r = 0; r < 4; ++r) {
                    int row = mt * 16 + quad * 4 + r;
                    int p = P0 + row;
                    float v = acc[mt][nt][r];
                    if (p < NB * NP) sf[(size_t)p * 128 + col] = v;
                    Slds[row * SSTR + col] = f2b(v);
                }
            }
    }
    __syncthreads();

    {
        int nc = wave * 64;
        f32x4 acc[2][4];
        #pragma unroll
        for (int mt = 0; mt < 2; ++mt)
            #pragma unroll
            for (int nt = 0; nt < 4; ++nt) acc[mt][nt] = (f32x4){0.f, 0.f, 0.f, 0.f};
        #pragma unroll
        for (int k8 = 0; k8 < 4; ++k8) {
            int ko = k8 * 32 + quad * 8;
            short8 a0 = *(const short8*)(&Slds[(n16) * SSTR + ko]);
            short8 a1 = *(const short8*)(&Slds[(16 + n16) * SSTR + ko]);
            #pragma unroll
            for (int nt = 0; nt < 4; ++nt) {
                short8 bfr = *(const short8*)(&ecw1t[(size_t)(nc + nt * 16 + n16) * 128 + ko]);
                acc[0][nt] = __builtin_amdgcn_mfma_f32_16x16x32_bf16(a0, bfr, acc[0][nt], 0, 0, 0);
                acc[1][nt] = __builtin_amdgcn_mfma_f32_16x16x32_bf16(a1, bfr, acc[1][nt], 0, 0, 0);
            }
        }
        #pragma unroll
        for (int mt = 0; mt < 2; ++mt)
            #pragma unroll
            for (int nt = 0; nt < 4; ++nt) {
                int colp = nc + nt * 16 + n16;
                float* dst = (colp < 128) ? hi : hj;
                int col = colp & 127;
                #pragma unroll
                for (int r = 0; r < 4; ++r) {
                    int row = mt * 16 + quad * 4 + r;
                    int p = P0 + row;
                    if (p < NB * NP) dst[(size_t)p * 128 + col] = acc[mt][nt][r];
                }
            }
    }
}

// ---------------- global max pool stage 1 ----------------
__global__ void gmax1_kernel(const float* __restrict__ sf, float* __restrict__ part) {
    int m = blockIdx.x;
    int b = m / 25, ch = m % 25, o = threadIdx.x;
    float v = -INFINITY;
    int n0 = ch * 40;
    for (int n = n0; n < n0 + 40; ++n)
        v = fmaxf(v, sf[((size_t)b * NP + n) * 128 + o]);
    part[(size_t)m * 128 + o] = v;
}

// ---------------- fused final max + hg = g @ W[256:384] + b1 ----------------
__global__ void gfin_kernel(const float* __restrict__ part, const float* __restrict__ w1,
                            const float* __restrict__ b1, float* __restrict__ hg) {
    int b = blockIdx.x, o = threadIdx.x;   // 128 threads
    __shared__ float gs[128];
    float v = -INFINITY;
    for (int ch = 0; ch < 25; ++ch)
        v = fmaxf(v, part[((size_t)b * 25 + ch) * 128 + o]);
    gs[o] = v;
    __syncthreads();
    float acc = b1[o];
    for (int c = 0; c < 128; ++c) acc += gs[c] * w1[(256 + c) * 128 + o];
    hg[b * 128 + o] = acc;
}

// ---------------- pairwise scorer over 32x32 tiles of (i,j), i<j ----------------
__global__ void pair_kernel(const float* __restrict__ hi, const float* __restrict__ hj,
                            const float* __restrict__ hg,
                            const float* __restrict__ w2, const float* __restrict__ b2,
                            void* __restrict__ out, const int* __restrict__ flag) {
    int j0 = blockIdx.x * 32, i0 = blockIdx.y * 32, b = blockIdx.z;
    if (j0 + 31 <= i0) return;
    __shared__ float hit[32][129];
    __shared__ float hjt[32][129];
    __shared__ float hgs[128];
    __shared__ float w2s[128];
    int tid = threadIdx.x;
    if (tid < 128) {
        hgs[tid] = hg[b * 128 + tid];
        w2s[tid] = w2[tid];
    }
    for (int t = tid; t < 32 * 128; t += 256) {
        int r = t >> 7, c = t & 127;
        int i = i0 + r, j = j0 + r;
        hit[r][c] = (i < NP) ? hi[((size_t)b * NP + i) * 128 + c] : 0.f;
        hjt[r][c] = (j < NP) ? hj[((size_t)b * NP + j) * 128 + c] : 0.f;
    }
    __syncthreads();
    float bb = b2[0];
    int f = flag[0];
    int tj = tid & 31;
    int ti0 = tid >> 5;
    int j = j0 + tj;
    float acc[4] = {0.f, 0.f, 0.f, 0.f};
    for (int o = 0; o < 128; ++o) {
        float hv = hjt[tj][o] + hgs[o];
        float wv = w2s[o];
        acc[0] += fmaxf(hit[ti0][o] + hv, 0.f) * wv;
        acc[1] += fmaxf(hit[ti0 + 8][o] + hv, 0.f) * wv;
        acc[2] += fmaxf(hit[ti0 + 16][o] + hv, 0.f) * wv;
        acc[3] += fmaxf(hit[ti0 + 24][o] + hv, 0.f) * wv;
    }
    for (int r = 0; r < 4; ++r) {
        int i = i0 + ti0 + 8 * r;
        if (i < j && j < NP) {
            size_t p = (size_t)i * (NP - 1) - (size_t)i * (i - 1) / 2 + (j - i - 1);
            float mo = acc[r] + bb;
            float pr = 1.f / (1.f + expf(-mo));
            size_t idx0 = (size_t)b * PPAIR + p;
            size_t idx1 = (size_t)NB * PPAIR + idx0;
            if (f) {
                ((float*)out)[idx0] = pr;
                ((float*)out)[idx1] = mo;
            } else {
                ((bf16*)out)[idx0] = __float2bfloat16(pr);
                ((bf16*)out)[idx1] = __float2bfloat16(mo);
            }
        }
    }
}

extern "C" void kernel_launch(void* const* d_in, const int* in_sizes, int n_in,
                              void* d_out, int out_size, void* d_ws, size_t ws_size,
                              hipStream_t stream) {
    float* ws = (float*)d_ws;
    float* posf = ws + OFF_POS;
    float* x1   = ws + OFF_X1;
    float* x2   = ws + OFF_X2;
    float* x3   = ws + OFF_X3;
    float* sf   = ws + OFF_SF;
    float* hi   = ws + OFF_HI;
    float* hj   = ws + OFF_HJ;
    float* hgb  = ws + OFF_HG;
    int*   flag = (int*)(ws + OFF_FLAG);
    int*   nidx = (int*)(ws + OFF_NIDX);
    float* gp   = ws + OFF_GP;
    ushort* w1t = (ushort*)(ws + OFF_W1T);
    ushort* w2t = (ushort*)(ws + OFF_W2T);
    ushort* smw1t = (ushort*)(ws + OFF_SMW1T);
    ushort* smw2t = (ushort*)(ws + OFF_SMW2T);
    ushort* ecw1t = (ushort*)(ws + OFF_ECW1T);

    // 1) detect input dtype (bf16 vs f32) on-device
    detect_kernel<<<1, 256, 0, stream>>>(d_in[0], flag);

    // 2) convert all inputs to f32 workspace; transpose/bf16 MFMA weights
    InPtrs ip;
    for (int i = 0; i < 21; ++i) ip.p[i] = d_in[i];
    dim3 cgrid(672, 21);
    cvt_all_kernel<<<cgrid, 256, 0, stream>>>(ip, ws, flag);
    dim3 wgrid(672, 5);
    wtrans_kernel<<<wgrid, 256, 0, stream>>>(ws, w1t, w2t, smw1t, smw2t, ecw1t);

    dim3 kgrid(NP / 8, NB);

    // 3) EdgeConv 1 (C=3 -> 32)
    knn_fused_kernel<3><<<kgrid, 256, 0, stream>>>(posf, nidx);
    edgeconv_kernel<3, 16, 32><<<NB * NP, 256, 0, stream>>>(
        posf, nidx, ws + OFF_C1W1, ws + OFF_C1B1, ws + OFF_C1W2, ws + OFF_C1B2, x1);

    // 4) EdgeConv 2 (C=32 -> 128)
    knn_fused_kernel<32><<<kgrid, 256, 0, stream>>>(x1, nidx);
    edgeconv_kernel<32, 64, 128><<<NB * NP, 256, 0, stream>>>(
        x1, nidx, ws + OFF_C2W1, ws + OFF_C2B1, ws + OFF_C2W2, ws + OFF_C2B2, x2);

    // 5) EdgeConv 3 (C=128 -> 512) via MFMA
    knn_fused_kernel<128><<<kgrid, 256, 0, stream>>>(x2, nidx);
    ec3_mfma_kernel<<<NB * NP / 4, 256, 0, stream>>>(
        x2, nidx, w1t, w2t, ws + OFF_C3B1, ws + OFF_C3B2, x3);

    // 6) shared MLP + hij via MFMA -> sf, hi, hj
    sm_mfma_kernel<<<(NB * NP + 31) / 32, 256, 0, stream>>>(
        x1, x2, x3, smw1t, smw2t, ecw1t, ws + OFF_SMB1, ws + OFF_SMB2, sf, hi, hj);

    // 7) global max pool + hg projection
    gmax1_kernel<<<NB * 25, 128, 0, stream>>>(sf, gp);
    gfin_kernel<<<NB, 128, 0, stream>>>(gp, ws + OFF_ECW1, ws + OFF_ECB1, hgb);

    // 8) pairwise scorer
    dim3 pgrid(32, 32, NB);
    pair_kernel<<<pgrid, 256, 0, stream>>>(hi, hj, hgb, ws + OFF_ECW2, ws + OFF_ECB2,
                                           d_out, flag);
}